// Round 18
// baseline (432.007 us; speedup 1.0000x reference)
//
#include <hip/hip_runtime.h>
#include <hip/hip_bf16.h>
#include <math.h>

#define B_DIM 2048
#define D_DIM 2048
#define H_DIM 512
#define Z_DIM 500

#define ACT_NONE 0
#define ACT_RELU 1
#define ACT_SIGMOID 2
#define ACT_LEAKY 3

typedef __attribute__((ext_vector_type(8))) _Float16 f16x8;
typedef __attribute__((ext_vector_type(4))) _Float16 f16x4;
typedef __attribute__((ext_vector_type(4))) float f32x4;
typedef __attribute__((ext_vector_type(2))) float f32x2;

__device__ __forceinline__ float rfl(float x) {
    return __uint_as_float(__builtin_amdgcn_readfirstlane(__float_as_uint(x)));
}

// ============ MFMA f16 GEMM, 128x64 tile, double-buffered, split-K ==========
// TERMS=3: 3-term split-f16 (fp32-class), BK=32. TERMS=1: plain f16, BK=64.
template<int BM, int BN, int TERMS, int BK>
__global__ __launch_bounds__(256, 2) void gemm_f16(
    const _Float16* __restrict__ Ah_, const _Float16* __restrict__ Al_,
    const _Float16* __restrict__ Bh_, const _Float16* __restrict__ Bl_,
    const float* __restrict__ bias, float* __restrict__ C,
    float* __restrict__ part, int M, int N, int K, int act, int Kc)
{
    constexpr int LDK = 40;
    constexpr int NPL = (TERMS == 3) ? 2 : 1;
    constexpr int NCH = BK / 32;
    constexpr int PSA = BM * LDK, PSB = BN * LDK;
    constexpr int CHUNK = NPL * (PSA + PSB);
    constexpr int BUF = NCH * CHUNK;
    constexpr int MT = BM / 32, NT = BN / 32;
    constexpr int CA = BM / 64, CB = BN / 64;
    __shared__ _Float16 smem[2 * BUF];

    const int t = threadIdx.x, lane = t & 63, wv = t >> 6;
    const int wrow = wv >> 1, wcol = wv & 1;
    const int row0 = blockIdx.y * BM, col0 = blockIdx.x * BN;
    const int ks = blockIdx.z * Kc;
    const int nk = Kc / BK;

    f16x8 rA[NCH][CA][NPL], rB[NCH][CB][NPL];

    auto gload = [&](int kt) {
        #pragma unroll
        for (int ch = 0; ch < NCH; ++ch) {
            int kc = kt + ch * 32;
            #pragma unroll
            for (int i = 0; i < CA; ++i) {
                int id = t + i * 256;
                int r = id >> 2, ko = (id & 3) * 8;
                size_t off = (size_t)(row0 + r) * K + kc + ko;
                rA[ch][i][0] = *(const f16x8*)(Ah_ + off);
                if constexpr (TERMS == 3) rA[ch][i][1] = *(const f16x8*)(Al_ + off);
            }
            #pragma unroll
            for (int i = 0; i < CB; ++i) {
                int id = t + i * 256;
                int r = id >> 2, ko = (id & 3) * 8;
                size_t off = (size_t)(col0 + r) * K + kc + ko;
                rB[ch][i][0] = *(const f16x8*)(Bh_ + off);
                if constexpr (TERMS == 3) rB[ch][i][1] = *(const f16x8*)(Bl_ + off);
            }
        }
    };
    auto cstore = [&](int b) {
        #pragma unroll
        for (int ch = 0; ch < NCH; ++ch) {
            _Float16* base = smem + b * BUF + ch * CHUNK;
            #pragma unroll
            for (int i = 0; i < CA; ++i) {
                int id = t + i * 256;
                int r = id >> 2, ko = (id & 3) * 8;
                *(f16x8*)&base[r * LDK + ko] = rA[ch][i][0];
                if constexpr (TERMS == 3) *(f16x8*)&base[PSA + r * LDK + ko] = rA[ch][i][1];
            }
            _Float16* bb = base + NPL * PSA;
            #pragma unroll
            for (int i = 0; i < CB; ++i) {
                int id = t + i * 256;
                int r = id >> 2, ko = (id & 3) * 8;
                *(f16x8*)&bb[r * LDK + ko] = rB[ch][i][0];
                if constexpr (TERMS == 3) *(f16x8*)&bb[PSB + r * LDK + ko] = rB[ch][i][1];
            }
        }
    };

    f32x4 acc[MT][NT];
    #pragma unroll
    for (int i = 0; i < MT; ++i)
        #pragma unroll
        for (int j = 0; j < NT; ++j) {
            f32x4 z = {0.f, 0.f, 0.f, 0.f};
            acc[i][j] = z;
        }

    const int q8 = (lane >> 4) * 8, fr = lane & 15;

    gload(ks);
    cstore(0);
    __syncthreads();

    for (int it = 0; it < nk; ++it) {
        int cur = it & 1;
        if (it + 1 < nk) gload(ks + (it + 1) * BK);

        #pragma unroll
        for (int ch = 0; ch < NCH; ++ch) {
            const _Float16* A0 = smem + cur * BUF + ch * CHUNK;
            const _Float16* A1 = A0 + PSA;
            const _Float16* B0 = A0 + NPL * PSA;
            const _Float16* B1 = B0 + PSB;
            f16x8 ah[MT], al[MT], bh[NT], bl[NT];
            #pragma unroll
            for (int i = 0; i < MT; ++i) {
                int r = wrow * (BM / 2) + i * 16 + fr;
                ah[i] = *(const f16x8*)&A0[r * LDK + q8];
                if constexpr (TERMS == 3) al[i] = *(const f16x8*)&A1[r * LDK + q8];
            }
            #pragma unroll
            for (int j = 0; j < NT; ++j) {
                int n = wcol * (BN / 2) + j * 16 + fr;
                bh[j] = *(const f16x8*)&B0[n * LDK + q8];
                if constexpr (TERMS == 3) bl[j] = *(const f16x8*)&B1[n * LDK + q8];
            }
            #pragma unroll
            for (int i = 0; i < MT; ++i)
                #pragma unroll
                for (int j = 0; j < NT; ++j) {
                    acc[i][j] = __builtin_amdgcn_mfma_f32_16x16x32_f16(ah[i], bh[j], acc[i][j], 0, 0, 0);
                    if constexpr (TERMS == 3) {
                        acc[i][j] = __builtin_amdgcn_mfma_f32_16x16x32_f16(ah[i], bl[j], acc[i][j], 0, 0, 0);
                        acc[i][j] = __builtin_amdgcn_mfma_f32_16x16x32_f16(al[i], bh[j], acc[i][j], 0, 0, 0);
                    }
                }
        }

        if (it + 1 < nk) cstore(cur ^ 1);
        __syncthreads();
    }

    const bool dopart = (gridDim.z > 1);
    float* dst = dopart ? (part + (size_t)blockIdx.z * M * N) : C;
    #pragma unroll
    for (int i = 0; i < MT; ++i) {
        int rbase = row0 + wrow * (BM / 2) + i * 16 + (lane >> 4) * 4;
        #pragma unroll
        for (int j = 0; j < NT; ++j) {
            int c = col0 + wcol * (BN / 2) + j * 16 + (lane & 15);
            if (c < N) {
                float b = dopart ? 0.f : bias[c];
                #pragma unroll
                for (int q = 0; q < 4; ++q) {
                    float v = acc[i][j][q] + b;
                    if (!dopart && act == ACT_SIGMOID)
                        v = 1.f / (1.f + __builtin_amdgcn_exp2f(-v * 1.44269504f));
                    dst[(size_t)(rbase + q) * N + c] = v;
                }
            }
        }
    }
}

// ============ converters ============
__global__ __launch_bounds__(256) void cvt_split_x(
    const float* __restrict__ x, _Float16* __restrict__ xh,
    _Float16* __restrict__ xl, int n4)
{
    int i = blockIdx.x * 256 + threadIdx.x;
    if (i >= n4) return;
    float4 v = ((const float4*)x)[i];
    f16x4 h, l;
    h[0]=(_Float16)v.x; l[0]=(_Float16)(v.x-(float)h[0]);
    h[1]=(_Float16)v.y; l[1]=(_Float16)(v.y-(float)h[1]);
    h[2]=(_Float16)v.z; l[2]=(_Float16)(v.z-(float)h[2]);
    h[3]=(_Float16)v.w; l[3]=(_Float16)(v.w-(float)h[3]);
    ((f16x4*)xh)[i] = h;
    ((f16x4*)xl)[i] = l;
}

__global__ __launch_bounds__(256) void cvt_w_t(
    const float* __restrict__ in, _Float16* __restrict__ outh,
    _Float16* __restrict__ outl, int K, int N, int Kp)
{
    __shared__ float tile[32][33];
    const int t = threadIdx.x;
    const int tk0 = blockIdx.x * 32, tn0 = blockIdx.y * 32;
    const int lx = t & 31, ly = t >> 5;
    #pragma unroll
    for (int r = 0; r < 4; ++r) {
        int k = tk0 + ly + r * 8, n = tn0 + lx;
        tile[ly + r * 8][lx] = (k < K && n < N) ? in[(size_t)k * N + n] : 0.f;
    }
    __syncthreads();
    #pragma unroll
    for (int r = 0; r < 4; ++r) {
        int n = tn0 + ly + r * 8, k = tk0 + lx;
        float v = tile[lx][ly + r * 8];
        _Float16 h = (_Float16)v;
        outh[(size_t)n * Kp + k] = h;
        if (outl) outl[(size_t)n * Kp + k] = (_Float16)(v - (float)h);
    }
}

// ===== fused heads reduce + reparameterize: part -> mu, lv, zb16 (padded) ====
// Thread per (row, c<512): reads head cols c and c+512 from partials.
__global__ __launch_bounds__(256) void reduce_heads_z(
    const float* __restrict__ part, int S,
    const float* __restrict__ b21, const float* __restrict__ b22,
    const float* __restrict__ eps, float* __restrict__ mu,
    float* __restrict__ lv, _Float16* __restrict__ zb)
{
    int i = blockIdx.x * 256 + threadIdx.x;
    if (i >= B_DIM * 512) return;
    int row = i >> 9, c = i & 511;
    if (c < Z_DIM) {
        const size_t MN = (size_t)B_DIM * 1024;
        size_t ia = (size_t)row * 1024 + c;
        float sm = b21[c], sl = b22[c];
        for (int k = 0; k < S; ++k) {
            sm += part[k * MN + ia];
            sl += part[k * MN + ia + 512];
        }
        size_t o = (size_t)row * Z_DIM + c;
        mu[o] = sm;
        lv[o] = sl;
        const float HL2E = 0.7213475204444817f;  // 0.5*log2(e)
        zb[(size_t)row * 512 + c] =
            (_Float16)(sm + eps[o] * __builtin_amdgcn_exp2f(sl * HL2E));
    } else {
        zb[(size_t)row * 512 + c] = (_Float16)0.f;
    }
}

// ============ fused split-K reduce + bias + BN column stats ============
__global__ __launch_bounds__(256) void reduce_stats(
    const float* __restrict__ part, int S, int Brows, int N, int rowsPerBlock,
    const float* __restrict__ bias, float* __restrict__ Y,
    float* __restrict__ statp)
{
    const int t = threadIdx.x;
    const int col = blockIdx.x * 64 + (t & 63);
    const int g = blockIdx.y;
    const int r0 = g * rowsPerBlock;
    const int r1 = min(r0 + rowsPerBlock, Brows);
    const size_t MN = (size_t)Brows * N;
    const float b = bias[col];
    float s = 0.f, s2 = 0.f;
    for (int r = r0 + (t >> 6); r < r1; r += 4) {
        float v = b;
        for (int k = 0; k < S; ++k) v += part[k * MN + (size_t)r * N + col];
        Y[(size_t)r * N + col] = v;
        s += v;
        s2 += v * v;
    }
    __shared__ float ss[4][64], ss2[4][64];
    ss[t >> 6][t & 63] = s;
    ss2[t >> 6][t & 63] = s2;
    __syncthreads();
    if (t < 64) {
        s  = ss[0][t] + ss[1][t] + ss[2][t] + ss[3][t];
        s2 = ss2[0][t] + ss2[1][t] + ss2[2][t] + ss2[3][t];
        float* p = statp + ((size_t)g * N + col) * 2;
        p[0] = s;
        p[1] = s2;
    }
}

__global__ __launch_bounds__(256) void colstats_final(
    const float* __restrict__ part, int G, int N, int Brows,
    const float* __restrict__ gamma, const float* __restrict__ beta,
    float* __restrict__ scale, float* __restrict__ shift)
{
    int c = blockIdx.x * 256 + threadIdx.x;
    if (c >= N) return;
    float s = 0.f, s2 = 0.f;
    for (int g = 0; g < G; ++g) {
        s  += part[((size_t)g * N + c) * 2];
        s2 += part[((size_t)g * N + c) * 2 + 1];
    }
    float invB = 1.f / (float)Brows;
    float mean = s * invB;
    float var  = s2 * invB - mean * mean;
    float rstd = rsqrtf(var + 1e-5f);
    float sc = gamma[c] * rstd;
    scale[c] = sc;
    shift[c] = beta[c] - mean * sc;
}

__global__ __launch_bounds__(256) void bn_apply_f16(
    const float* __restrict__ Y, const float* __restrict__ scale,
    const float* __restrict__ shift, _Float16* __restrict__ oh,
    _Float16* __restrict__ ol, int total, int N, int act)
{
    int idx = blockIdx.x * 256 + threadIdx.x;
    int i4 = idx * 4;
    if (i4 >= total) return;
    float4 y = *(const float4*)(Y + i4);
    int c = i4 % N;
    float4 sc = *(const float4*)(scale + c);
    float4 sh = *(const float4*)(shift + c);
    float r[4];
    r[0] = y.x * sc.x + sh.x;
    r[1] = y.y * sc.y + sh.y;
    r[2] = y.z * sc.z + sh.z;
    r[3] = y.w * sc.w + sh.w;
    #pragma unroll
    for (int q = 0; q < 4; ++q) {
        if (act == ACT_RELU) r[q] = fmaxf(r[q], 0.f);
        else if (act == ACT_LEAKY) r[q] = (r[q] >= 0.f) ? r[q] : 0.01f * r[q];
    }
    f16x4 h;
    #pragma unroll
    for (int q = 0; q < 4; ++q) h[q] = (_Float16)r[q];
    ((f16x4*)oh)[idx] = h;
    if (ol) {
        f16x4 l;
        #pragma unroll
        for (int q = 0; q < 4; ++q) l[q] = (_Float16)(r[q] - (float)h[q]);
        ((f16x4*)ol)[idx] = l;
    }
}

// ============ Gumbel subset scan v7: TWO rows per block, interleaved =========
// v4's structure/recurrence, but each 256-thread block processes rows 2b and
// 2b+1 simultaneously. Row B's VALU work hides row A's reduce latency; the
// two rows share one barrier + one f32x4 LDS slot {lmA,sA,lmB,sB} per wave.
// State 2x12 f32x2 = 48 VGPR (under the ~64 remat threshold that hit v5).
__global__ __launch_bounds__(256) void gumbel_scan(
    const float* __restrict__ WLg, const float* __restrict__ U,
    const float* __restrict__ X, _Float16* __restrict__ XM)
{
    const int t = threadIdx.x, wv = t >> 6, lane = t & 63;
    const size_t base = (size_t)(blockIdx.x * 2) * D_DIM + 8 * t;
    const float* wA = WLg + base;  const float* wB = wA + D_DIM;
    const float* uA = U + base;    const float* uB = uA + D_DIM;
    const float* xA = X + base;    const float* xB = xA + D_DIM;
    _Float16* oA = XM + base;      _Float16* oB = oA + D_DIM;

    const float L2E = 1.4426950408889634f;
    const float LOG2LN2 = -0.5287663729448977f;

    __shared__ f32x4 sLS[2][4];
    __shared__ f32x2 sM0[4];

    f32x2 WA[4], eA[4], aA[4];
    f32x2 WB[4], eB[4], aB[4];

    auto mkW = [&](float wl, float uu) -> float {
        float u = fmaf(uu, 1.0f - 1e-10f, 1e-10f);
        float tl = -__builtin_amdgcn_logf(u);
        return __builtin_amdgcn_exp2f(fmaf(wl, L2E, __builtin_amdgcn_logf(tl) + LOG2LN2));
    };

    {
        float4 u4a = *(const float4*)uA, u4b = *(const float4*)(uA + 4);
        float4 w4a = *(const float4*)wA, w4b = *(const float4*)(wA + 4);
        WA[0] = f32x2{mkW(w4a.x, u4a.x), mkW(w4a.y, u4a.y)};
        WA[1] = f32x2{mkW(w4a.z, u4a.z), mkW(w4a.w, u4a.w)};
        WA[2] = f32x2{mkW(w4b.x, u4b.x), mkW(w4b.y, u4b.y)};
        WA[3] = f32x2{mkW(w4b.z, u4b.z), mkW(w4b.w, u4b.w)};
        u4a = *(const float4*)uB; u4b = *(const float4*)(uB + 4);
        w4a = *(const float4*)wB; w4b = *(const float4*)(wB + 4);
        WB[0] = f32x2{mkW(w4a.x, u4a.x), mkW(w4a.y, u4a.y)};
        WB[1] = f32x2{mkW(w4a.z, u4a.z), mkW(w4a.w, u4a.w)};
        WB[2] = f32x2{mkW(w4b.x, u4b.x), mkW(w4b.y, u4b.y)};
        WB[3] = f32x2{mkW(w4b.z, u4b.z), mkW(w4b.w, u4b.w)};
    }
    #pragma unroll
    for (int j = 0; j < 4; ++j) {
        eA[j] = f32x2{0.f, 0.f}; aA[j] = f32x2{0.f, 0.f};
        eB[j] = f32x2{0.f, 0.f}; aB[j] = f32x2{0.f, 0.f};
    }

    float rmA, rmB;
    {
        float la = 0.f, lb = 0.f;
        #pragma unroll
        for (int j = 0; j < 4; ++j) {
            la = fmaxf(la, fmaxf(WA[j].x, WA[j].y));
            lb = fmaxf(lb, fmaxf(WB[j].x, WB[j].y));
        }
        #pragma unroll
        for (int off = 32; off; off >>= 1) {
            la = fmaxf(la, __shfl_xor(la, off));
            lb = fmaxf(lb, __shfl_xor(lb, off));
        }
        if (lane == 0) sM0[wv] = f32x2{la, lb};
        __syncthreads();
        f32x2 m0 = sM0[0], m1 = sM0[1], m2 = sM0[2], m3 = sM0[3];
        rmA = rfl(__builtin_amdgcn_rcpf(fmaxf(fmaxf(m0.x, m1.x), fmaxf(m2.x, m3.x))));
        rmB = rfl(__builtin_amdgcn_rcpf(fmaxf(fmaxf(m0.y, m1.y), fmaxf(m2.y, m3.y))));
    }

    float invA = 0.f, invB = 0.f;
    int gi = 0;

    auto iterate = [&](bool refresh) {
        const int p = gi & 1;
        ++gi;
        f32x2 lvA = f32x2{0.f, 0.f}, svA = f32x2{0.f, 0.f};
        f32x2 lvB = f32x2{0.f, 0.f}, svB = f32x2{0.f, 0.f};
        #pragma unroll
        for (int j = 0; j < 4; ++j) {
            // row A
            aA[j].x = fmaf(eA[j].x, invA, aA[j].x);
            aA[j].y = fmaf(eA[j].y, invA, aA[j].y);
            f32x2 mk;
            mk.x = fmaxf(fmaf(-eA[j].x, invA, 1.0f), 1e-10f);
            mk.y = fmaxf(fmaf(-eA[j].y, invA, 1.0f), 1e-10f);
            f32x2 Wn = WA[j] * mk;
            WA[j] = Wn;
            f32x2 r;
            r.x = Wn.x * rmA; r.y = Wn.y * rmA;
            f32x2 q2 = r * r, q4 = q2 * q2, q8 = q4 * q4;
            f32x2 ee = q8 * q2;
            eA[j] = ee;
            svA += ee;
            if (refresh) { lvA.x = fmaxf(lvA.x, Wn.x); lvA.y = fmaxf(lvA.y, Wn.y); }
            // row B
            aB[j].x = fmaf(eB[j].x, invB, aB[j].x);
            aB[j].y = fmaf(eB[j].y, invB, aB[j].y);
            mk.x = fmaxf(fmaf(-eB[j].x, invB, 1.0f), 1e-10f);
            mk.y = fmaxf(fmaf(-eB[j].y, invB, 1.0f), 1e-10f);
            Wn = WB[j] * mk;
            WB[j] = Wn;
            r.x = Wn.x * rmB; r.y = Wn.y * rmB;
            q2 = r * r; q4 = q2 * q2; q8 = q4 * q4;
            ee = q8 * q2;
            eB[j] = ee;
            svB += ee;
            if (refresh) { lvB.x = fmaxf(lvB.x, Wn.x); lvB.y = fmaxf(lvB.y, Wn.y); }
        }
        float sa = svA.x + svA.y, sb = svB.x + svB.y;
        if (refresh) {
            float la = fmaxf(lvA.x, lvA.y), lb = fmaxf(lvB.x, lvB.y);
            #pragma unroll
            for (int off = 32; off; off >>= 1) {
                sa += __shfl_xor(sa, off);
                sb += __shfl_xor(sb, off);
                la = fmaxf(la, __shfl_xor(la, off));
                lb = fmaxf(lb, __shfl_xor(lb, off));
            }
            if (lane == 0) sLS[p][wv] = f32x4{la, sa, lb, sb};
            __syncthreads();
            f32x4 r0 = sLS[p][0], r1 = sLS[p][1], r2 = sLS[p][2], r3 = sLS[p][3];
            rmA = rfl(__builtin_amdgcn_rcpf(fmaxf(fmaxf(r0[0], r1[0]), fmaxf(r2[0], r3[0]))));
            invA = rfl(__builtin_amdgcn_rcpf((r0[1] + r1[1]) + (r2[1] + r3[1])));
            rmB = rfl(__builtin_amdgcn_rcpf(fmaxf(fmaxf(r0[2], r1[2]), fmaxf(r2[2], r3[2]))));
            invB = rfl(__builtin_amdgcn_rcpf((r0[3] + r1[3]) + (r2[3] + r3[3])));
        } else {
            #pragma unroll
            for (int off = 32; off; off >>= 1) {
                sa += __shfl_xor(sa, off);
                sb += __shfl_xor(sb, off);
            }
            if (lane == 0) { sLS[p][wv][1] = sa; sLS[p][wv][3] = sb; }
            __syncthreads();
            f32x4 r0 = sLS[p][0], r1 = sLS[p][1], r2 = sLS[p][2], r3 = sLS[p][3];
            invA = rfl(__builtin_amdgcn_rcpf((r0[1] + r1[1]) + (r2[1] + r3[1])));
            invB = rfl(__builtin_amdgcn_rcpf((r0[3] + r1[3]) + (r2[3] + r3[3])));
        }
    };

    for (int ot = 0; ot < 16; ++ot) {
        iterate(false);
        iterate(false);
        iterate(false);
        iterate(true);
    }

    {
        float4 xa = *(const float4*)xA, xb = *(const float4*)(xA + 4);
        f16x8 o;
        o[0] = (_Float16)(xa.x * fmaf(eA[0].x, invA, aA[0].x));
        o[1] = (_Float16)(xa.y * fmaf(eA[0].y, invA, aA[0].y));
        o[2] = (_Float16)(xa.z * fmaf(eA[1].x, invA, aA[1].x));
        o[3] = (_Float16)(xa.w * fmaf(eA[1].y, invA, aA[1].y));
        o[4] = (_Float16)(xb.x * fmaf(eA[2].x, invA, aA[2].x));
        o[5] = (_Float16)(xb.y * fmaf(eA[2].y, invA, aA[2].y));
        o[6] = (_Float16)(xb.z * fmaf(eA[3].x, invA, aA[3].x));
        o[7] = (_Float16)(xb.w * fmaf(eA[3].y, invA, aA[3].y));
        *(f16x8*)oA = o;
        xa = *(const float4*)xB; xb = *(const float4*)(xB + 4);
        o[0] = (_Float16)(xa.x * fmaf(eB[0].x, invB, aB[0].x));
        o[1] = (_Float16)(xa.y * fmaf(eB[0].y, invB, aB[0].y));
        o[2] = (_Float16)(xa.z * fmaf(eB[1].x, invB, aB[1].x));
        o[3] = (_Float16)(xa.w * fmaf(eB[1].y, invB, aB[1].y));
        o[4] = (_Float16)(xb.x * fmaf(eB[2].x, invB, aB[2].x));
        o[5] = (_Float16)(xb.y * fmaf(eB[2].y, invB, aB[2].y));
        o[6] = (_Float16)(xb.z * fmaf(eB[3].x, invB, aB[3].x));
        o[7] = (_Float16)(xb.w * fmaf(eB[3].y, invB, aB[3].y));
        *(f16x8*)oB = o;
    }
}

extern "C" void kernel_launch(void* const* d_in, const int* in_sizes, int n_in,
                              void* d_out, int out_size, void* d_ws, size_t ws_size,
                              hipStream_t stream) {
    const float* x        = (const float*)d_in[0];
    const float* u_gumbel = (const float*)d_in[1];
    const float* eps      = (const float*)d_in[2];
    const float* wc_w1    = (const float*)d_in[3];
    const float* wc_b1    = (const float*)d_in[4];
    const float* wc_g     = (const float*)d_in[5];
    const float* wc_beta  = (const float*)d_in[6];
    const float* wc_w2    = (const float*)d_in[7];
    const float* wc_b2    = (const float*)d_in[8];
    const float* enc_w1   = (const float*)d_in[9];
    const float* enc_b1   = (const float*)d_in[10];
    const float* enc_g1   = (const float*)d_in[11];
    const float* enc_beta1= (const float*)d_in[12];
    const float* enc_w2   = (const float*)d_in[13];
    const float* enc_b2   = (const float*)d_in[14];
    const float* enc_g2   = (const float*)d_in[15];
    const float* enc_beta2= (const float*)d_in[16];
    const float* enc_w3   = (const float*)d_in[17];
    const float* enc_b3   = (const float*)d_in[18];
    const float* enc_g3   = (const float*)d_in[19];
    const float* enc_beta3= (const float*)d_in[20];
    const float* fc21_w   = (const float*)d_in[21];
    const float* fc21_b   = (const float*)d_in[22];
    const float* fc22_w   = (const float*)d_in[23];
    const float* fc22_b   = (const float*)d_in[24];
    const float* fc3_w    = (const float*)d_in[25];
    const float* fc3_b    = (const float*)d_in[26];
    const float* fc3_g    = (const float*)d_in[27];
    const float* fc3_beta = (const float*)d_in[28];
    const float* fc4_w    = (const float*)d_in[29];
    const float* fc4_b    = (const float*)d_in[30];

    float* out   = (float*)d_out;
    float* mu_x  = out;
    float* mu    = out + (size_t)B_DIM * D_DIM;
    float* lv    = mu + (size_t)B_DIM * Z_DIM;

    const size_t F1M = 1u << 20;
    float* wsf = (float*)d_ws;
    float*     P_WL  = wsf;
    _Float16*  xh    = (_Float16*)(wsf + 4 * F1M);
    _Float16*  xl    = (_Float16*)(wsf + 6 * F1M);
    _Float16*  xm16  = (_Float16*)(wsf + 4 * F1M);
    float*     Yb    = wsf + 6 * F1M;
    _Float16*  a2    = (_Float16*)(wsf + 8 * F1M);
    _Float16*  a3    = (_Float16*)(wsf + 9 * F1M);
    _Float16*  a4    = (_Float16*)(wsf + 9 * F1M + F1M / 2);
    _Float16*  zb16  = (_Float16*)(wsf + 10 * F1M);
    _Float16*  a5    = (_Float16*)(wsf + 10 * F1M + F1M / 2);
    float*     Hbuf  = wsf + 11 * F1M;
    _Float16*  Hh    = (_Float16*)(wsf + 12 * F1M);
    _Float16*  Hl    = (_Float16*)(wsf + 12 * F1M + F1M / 2);
    _Float16*  w1th  = (_Float16*)(wsf + 13 * F1M);
    _Float16*  w1tl  = (_Float16*)(wsf + 13 * F1M + F1M / 2);
    _Float16*  w2th  = (_Float16*)(wsf + 14 * F1M);
    _Float16*  w2tl  = (_Float16*)(wsf + 14 * F1M + F1M / 2);
    _Float16*  e1t   = (_Float16*)(wsf + 15 * F1M);
    _Float16*  e2t   = (_Float16*)(wsf + 16 * F1M);
    _Float16*  e3t   = (_Float16*)(wsf + 16 * F1M + F1M / 4);
    _Float16*  f21t  = (_Float16*)(wsf + 16 * F1M + 3 * (F1M / 8));
    _Float16*  f22t  = (_Float16*)(wsf + 16 * F1M + 4 * (F1M / 8));  // contiguous after f21t
    _Float16*  f3t   = (_Float16*)(wsf + 16 * F1M + 5 * (F1M / 8));
    _Float16*  f4t   = (_Float16*)(wsf + 16 * F1M + 6 * (F1M / 8));
    float*     bnp   = wsf + 17 * F1M + F1M / 4;
    float*     scale = bnp + 131072;
    float*     shift = scale + 2048;

    const int G = 64;

    auto gemm3 = [&](const _Float16* Ah, const _Float16* Al,
                     const _Float16* Bh, const _Float16* Bl,
                     const float* b, float* C, float* part,
                     int N, int K, int SK) {
        dim3 grid((N + 63) / 64, B_DIM / 128, SK);
        gemm_f16<128, 64, 3, 32><<<grid, 256, 0, stream>>>(Ah, Al, Bh, Bl, b, C, part,
                                                           B_DIM, N, K, ACT_NONE, K / SK);
    };
    auto gemm1 = [&](const _Float16* Ah, const _Float16* Bh,
                     const float* b, float* C, float* part,
                     int N, int K, int act, int SK) {
        dim3 grid((N + 63) / 64, B_DIM / 128, SK);
        gemm_f16<128, 64, 1, 64><<<grid, 256, 0, stream>>>(Ah, nullptr, Bh, nullptr, b, C,
                                                           part, B_DIM, N, K, act, K / SK);
    };
    auto bnFromParts = [&](const float* part, int S, const float* b,
                           const float* g_, const float* beta_,
                           float* Y, _Float16* oh, _Float16* ol, int N, int act) {
        dim3 gp(N / 64, G);
        reduce_stats<<<gp, 256, 0, stream>>>(part, S, B_DIM, N, B_DIM / G, b, Y, bnp);
        colstats_final<<<(N + 255) / 256, 256, 0, stream>>>(bnp, G, N, B_DIM, g_, beta_, scale, shift);
        int total = B_DIM * N;
        bn_apply_f16<<<(total / 4 + 255) / 256, 256, 0, stream>>>(Y, scale, shift, oh, ol, total, N, act);
    };
    auto cvtw = [&](const float* in, _Float16* oh, _Float16* ol, int K, int N, int Kp, int Np) {
        dim3 grid(Kp / 32, Np / 32);
        cvt_w_t<<<grid, 256, 0, stream>>>(in, oh, ol, K, N, Kp);
    };

    // ---- converts ----
    cvt_split_x<<<4096, 256, 0, stream>>>(x, xh, xl, B_DIM * D_DIM / 4);
    cvtw(wc_w1, w1th, w1tl, 2048, 512, 2048, 512);
    cvtw(wc_w2, w2th, w2tl, 512, 2048, 512, 2048);
    cvtw(enc_w1, e1t, nullptr, 2048, 1024, 2048, 1024);
    cvtw(enc_w2, e2t, nullptr, 1024, 512, 1024, 512);
    cvtw(enc_w3, e3t, nullptr, 512, 512, 512, 512);
    cvtw(fc21_w, f21t, nullptr, 512, 500, 512, 512);
    cvtw(fc22_w, f22t, nullptr, 512, 500, 512, 512);
    cvtw(fc3_w, f3t, nullptr, 500, 512, 512, 512);
    cvtw(fc4_w, f4t, nullptr, 512, 2048, 512, 2048);

    // ---- weight_creator ----
    gemm3(xh, xl, w1th, w1tl, nullptr, nullptr, P_WL, 512, 2048, 4);
    bnFromParts(P_WL, 4, wc_b1, wc_g, wc_beta, Hbuf, Hh, Hl, 512, ACT_RELU);
    gemm3(Hh, Hl, w2th, w2tl, wc_b2, P_WL, nullptr, 2048, 512, 1);  // -> WL

    // ---- gumbel scan: WL -> xm16 (f16), 2 rows per block ----
    gumbel_scan<<<B_DIM / 2, 256, 0, stream>>>(P_WL, u_gumbel, x, xm16);

    // ---- encoder ----
    gemm1(xm16, e1t, nullptr, nullptr, P_WL, 1024, 2048, ACT_NONE, 2);
    bnFromParts(P_WL, 2, enc_b1, enc_g1, enc_beta1, Yb, a2, nullptr, 1024, ACT_LEAKY);
    gemm1(a2, e2t, nullptr, nullptr, P_WL, 512, 1024, ACT_NONE, 4);
    bnFromParts(P_WL, 4, enc_b2, enc_g2, enc_beta2, Yb, a3, nullptr, 512, ACT_LEAKY);
    gemm1(a3, e3t, nullptr, nullptr, P_WL, 512, 512, ACT_NONE, 4);
    bnFromParts(P_WL, 4, enc_b3, enc_g3, enc_beta3, Yb, a4, nullptr, 512, ACT_LEAKY);

    // ---- heads: combined GEMM + fused reduce/reparam (mu, lv, zb16) ----
    gemm1(a4, f21t, nullptr, nullptr, P_WL, 1024, 512, ACT_NONE, 4);
    reduce_heads_z<<<(B_DIM * 512 + 255) / 256, 256, 0, stream>>>(
        P_WL, 4, fc21_b, fc22_b, eps, mu, lv, zb16);

    // ---- decoder ----
    gemm1(zb16, f3t, nullptr, nullptr, P_WL, 512, 512, ACT_NONE, 4);
    bnFromParts(P_WL, 4, fc3_b, fc3_g, fc3_beta, Yb, a5, nullptr, 512, ACT_LEAKY);
    gemm1(a5, f4t, fc4_b, mu_x, nullptr, 2048, 512, ACT_SIGMOID, 1);
}

// Round 19
// 417.495 us; speedup vs baseline: 1.0348x; 1.0348x over previous
//
#include <hip/hip_runtime.h>
#include <hip/hip_bf16.h>
#include <math.h>

#define B_DIM 2048
#define D_DIM 2048
#define H_DIM 512
#define Z_DIM 500

#define ACT_NONE 0
#define ACT_RELU 1
#define ACT_SIGMOID 2
#define ACT_LEAKY 3

typedef __attribute__((ext_vector_type(8))) _Float16 f16x8;
typedef __attribute__((ext_vector_type(4))) _Float16 f16x4;
typedef __attribute__((ext_vector_type(4))) float f32x4;
typedef __attribute__((ext_vector_type(2))) float f32x2;

__device__ __forceinline__ float rfl(float x) {
    return __uint_as_float(__builtin_amdgcn_readfirstlane(__float_as_uint(x)));
}

// ============ MFMA f16 GEMM, 128x64 tile, double-buffered, split-K ==========
// TERMS=3: 3-term split-f16 (fp32-class), BK=32. TERMS=1: plain f16, BK=64.
template<int BM, int BN, int TERMS, int BK>
__global__ __launch_bounds__(256, 2) void gemm_f16(
    const _Float16* __restrict__ Ah_, const _Float16* __restrict__ Al_,
    const _Float16* __restrict__ Bh_, const _Float16* __restrict__ Bl_,
    const float* __restrict__ bias, float* __restrict__ C,
    float* __restrict__ part, int M, int N, int K, int act, int Kc)
{
    constexpr int LDK = 40;
    constexpr int NPL = (TERMS == 3) ? 2 : 1;
    constexpr int NCH = BK / 32;
    constexpr int PSA = BM * LDK, PSB = BN * LDK;
    constexpr int CHUNK = NPL * (PSA + PSB);
    constexpr int BUF = NCH * CHUNK;
    constexpr int MT = BM / 32, NT = BN / 32;
    constexpr int CA = BM / 64, CB = BN / 64;
    __shared__ _Float16 smem[2 * BUF];

    const int t = threadIdx.x, lane = t & 63, wv = t >> 6;
    const int wrow = wv >> 1, wcol = wv & 1;
    const int row0 = blockIdx.y * BM, col0 = blockIdx.x * BN;
    const int ks = blockIdx.z * Kc;
    const int nk = Kc / BK;

    f16x8 rA[NCH][CA][NPL], rB[NCH][CB][NPL];

    auto gload = [&](int kt) {
        #pragma unroll
        for (int ch = 0; ch < NCH; ++ch) {
            int kc = kt + ch * 32;
            #pragma unroll
            for (int i = 0; i < CA; ++i) {
                int id = t + i * 256;
                int r = id >> 2, ko = (id & 3) * 8;
                size_t off = (size_t)(row0 + r) * K + kc + ko;
                rA[ch][i][0] = *(const f16x8*)(Ah_ + off);
                if constexpr (TERMS == 3) rA[ch][i][1] = *(const f16x8*)(Al_ + off);
            }
            #pragma unroll
            for (int i = 0; i < CB; ++i) {
                int id = t + i * 256;
                int r = id >> 2, ko = (id & 3) * 8;
                size_t off = (size_t)(col0 + r) * K + kc + ko;
                rB[ch][i][0] = *(const f16x8*)(Bh_ + off);
                if constexpr (TERMS == 3) rB[ch][i][1] = *(const f16x8*)(Bl_ + off);
            }
        }
    };
    auto cstore = [&](int b) {
        #pragma unroll
        for (int ch = 0; ch < NCH; ++ch) {
            _Float16* base = smem + b * BUF + ch * CHUNK;
            #pragma unroll
            for (int i = 0; i < CA; ++i) {
                int id = t + i * 256;
                int r = id >> 2, ko = (id & 3) * 8;
                *(f16x8*)&base[r * LDK + ko] = rA[ch][i][0];
                if constexpr (TERMS == 3) *(f16x8*)&base[PSA + r * LDK + ko] = rA[ch][i][1];
            }
            _Float16* bb = base + NPL * PSA;
            #pragma unroll
            for (int i = 0; i < CB; ++i) {
                int id = t + i * 256;
                int r = id >> 2, ko = (id & 3) * 8;
                *(f16x8*)&bb[r * LDK + ko] = rB[ch][i][0];
                if constexpr (TERMS == 3) *(f16x8*)&bb[PSB + r * LDK + ko] = rB[ch][i][1];
            }
        }
    };

    f32x4 acc[MT][NT];
    #pragma unroll
    for (int i = 0; i < MT; ++i)
        #pragma unroll
        for (int j = 0; j < NT; ++j) {
            f32x4 z = {0.f, 0.f, 0.f, 0.f};
            acc[i][j] = z;
        }

    const int q8 = (lane >> 4) * 8, fr = lane & 15;

    gload(ks);
    cstore(0);
    __syncthreads();

    for (int it = 0; it < nk; ++it) {
        int cur = it & 1;
        if (it + 1 < nk) gload(ks + (it + 1) * BK);

        #pragma unroll
        for (int ch = 0; ch < NCH; ++ch) {
            const _Float16* A0 = smem + cur * BUF + ch * CHUNK;
            const _Float16* A1 = A0 + PSA;
            const _Float16* B0 = A0 + NPL * PSA;
            const _Float16* B1 = B0 + PSB;
            f16x8 ah[MT], al[MT], bh[NT], bl[NT];
            #pragma unroll
            for (int i = 0; i < MT; ++i) {
                int r = wrow * (BM / 2) + i * 16 + fr;
                ah[i] = *(const f16x8*)&A0[r * LDK + q8];
                if constexpr (TERMS == 3) al[i] = *(const f16x8*)&A1[r * LDK + q8];
            }
            #pragma unroll
            for (int j = 0; j < NT; ++j) {
                int n = wcol * (BN / 2) + j * 16 + fr;
                bh[j] = *(const f16x8*)&B0[n * LDK + q8];
                if constexpr (TERMS == 3) bl[j] = *(const f16x8*)&B1[n * LDK + q8];
            }
            #pragma unroll
            for (int i = 0; i < MT; ++i)
                #pragma unroll
                for (int j = 0; j < NT; ++j) {
                    acc[i][j] = __builtin_amdgcn_mfma_f32_16x16x32_f16(ah[i], bh[j], acc[i][j], 0, 0, 0);
                    if constexpr (TERMS == 3) {
                        acc[i][j] = __builtin_amdgcn_mfma_f32_16x16x32_f16(ah[i], bl[j], acc[i][j], 0, 0, 0);
                        acc[i][j] = __builtin_amdgcn_mfma_f32_16x16x32_f16(al[i], bh[j], acc[i][j], 0, 0, 0);
                    }
                }
        }

        if (it + 1 < nk) cstore(cur ^ 1);
        __syncthreads();
    }

    const bool dopart = (gridDim.z > 1);
    float* dst = dopart ? (part + (size_t)blockIdx.z * M * N) : C;
    #pragma unroll
    for (int i = 0; i < MT; ++i) {
        int rbase = row0 + wrow * (BM / 2) + i * 16 + (lane >> 4) * 4;
        #pragma unroll
        for (int j = 0; j < NT; ++j) {
            int c = col0 + wcol * (BN / 2) + j * 16 + (lane & 15);
            if (c < N) {
                float b = dopart ? 0.f : bias[c];
                #pragma unroll
                for (int q = 0; q < 4; ++q) {
                    float v = acc[i][j][q] + b;
                    if (!dopart && act == ACT_SIGMOID)
                        v = 1.f / (1.f + __builtin_amdgcn_exp2f(-v * 1.44269504f));
                    dst[(size_t)(rbase + q) * N + c] = v;
                }
            }
        }
    }
}

// ============ converters ============
__global__ __launch_bounds__(256) void cvt_split_x(
    const float* __restrict__ x, _Float16* __restrict__ xh,
    _Float16* __restrict__ xl, int n4)
{
    int i = blockIdx.x * 256 + threadIdx.x;
    if (i >= n4) return;
    float4 v = ((const float4*)x)[i];
    f16x4 h, l;
    h[0]=(_Float16)v.x; l[0]=(_Float16)(v.x-(float)h[0]);
    h[1]=(_Float16)v.y; l[1]=(_Float16)(v.y-(float)h[1]);
    h[2]=(_Float16)v.z; l[2]=(_Float16)(v.z-(float)h[2]);
    h[3]=(_Float16)v.w; l[3]=(_Float16)(v.w-(float)h[3]);
    ((f16x4*)xh)[i] = h;
    ((f16x4*)xl)[i] = l;
}

__global__ __launch_bounds__(256) void cvt_w_t(
    const float* __restrict__ in, _Float16* __restrict__ outh,
    _Float16* __restrict__ outl, int K, int N, int Kp)
{
    __shared__ float tile[32][33];
    const int t = threadIdx.x;
    const int tk0 = blockIdx.x * 32, tn0 = blockIdx.y * 32;
    const int lx = t & 31, ly = t >> 5;
    #pragma unroll
    for (int r = 0; r < 4; ++r) {
        int k = tk0 + ly + r * 8, n = tn0 + lx;
        tile[ly + r * 8][lx] = (k < K && n < N) ? in[(size_t)k * N + n] : 0.f;
    }
    __syncthreads();
    #pragma unroll
    for (int r = 0; r < 4; ++r) {
        int n = tn0 + ly + r * 8, k = tk0 + lx;
        float v = tile[lx][ly + r * 8];
        _Float16 h = (_Float16)v;
        outh[(size_t)n * Kp + k] = h;
        if (outl) outl[(size_t)n * Kp + k] = (_Float16)(v - (float)h);
    }
}

// ===== fused heads reduce + reparameterize: part -> mu, lv, zb16 (padded) ====
__global__ __launch_bounds__(256) void reduce_heads_z(
    const float* __restrict__ part, int S,
    const float* __restrict__ b21, const float* __restrict__ b22,
    const float* __restrict__ eps, float* __restrict__ mu,
    float* __restrict__ lv, _Float16* __restrict__ zb)
{
    int i = blockIdx.x * 256 + threadIdx.x;
    if (i >= B_DIM * 512) return;
    int row = i >> 9, c = i & 511;
    if (c < Z_DIM) {
        const size_t MN = (size_t)B_DIM * 1024;
        size_t ia = (size_t)row * 1024 + c;
        float sm = b21[c], sl = b22[c];
        for (int k = 0; k < S; ++k) {
            sm += part[k * MN + ia];
            sl += part[k * MN + ia + 512];
        }
        size_t o = (size_t)row * Z_DIM + c;
        mu[o] = sm;
        lv[o] = sl;
        const float HL2E = 0.7213475204444817f;  // 0.5*log2(e)
        zb[(size_t)row * 512 + c] =
            (_Float16)(sm + eps[o] * __builtin_amdgcn_exp2f(sl * HL2E));
    } else {
        zb[(size_t)row * 512 + c] = (_Float16)0.f;
    }
}

// ============ fused split-K reduce + bias + BN column stats ============
__global__ __launch_bounds__(256) void reduce_stats(
    const float* __restrict__ part, int S, int Brows, int N, int rowsPerBlock,
    const float* __restrict__ bias, float* __restrict__ Y,
    float* __restrict__ statp)
{
    const int t = threadIdx.x;
    const int col = blockIdx.x * 64 + (t & 63);
    const int g = blockIdx.y;
    const int r0 = g * rowsPerBlock;
    const int r1 = min(r0 + rowsPerBlock, Brows);
    const size_t MN = (size_t)Brows * N;
    const float b = bias[col];
    float s = 0.f, s2 = 0.f;
    for (int r = r0 + (t >> 6); r < r1; r += 4) {
        float v = b;
        for (int k = 0; k < S; ++k) v += part[k * MN + (size_t)r * N + col];
        Y[(size_t)r * N + col] = v;
        s += v;
        s2 += v * v;
    }
    __shared__ float ss[4][64], ss2[4][64];
    ss[t >> 6][t & 63] = s;
    ss2[t >> 6][t & 63] = s2;
    __syncthreads();
    if (t < 64) {
        s  = ss[0][t] + ss[1][t] + ss[2][t] + ss[3][t];
        s2 = ss2[0][t] + ss2[1][t] + ss2[2][t] + ss2[3][t];
        float* p = statp + ((size_t)g * N + col) * 2;
        p[0] = s;
        p[1] = s2;
    }
}

__global__ __launch_bounds__(256) void colstats_final(
    const float* __restrict__ part, int G, int N, int Brows,
    const float* __restrict__ gamma, const float* __restrict__ beta,
    float* __restrict__ scale, float* __restrict__ shift)
{
    int c = blockIdx.x * 256 + threadIdx.x;
    if (c >= N) return;
    float s = 0.f, s2 = 0.f;
    for (int g = 0; g < G; ++g) {
        s  += part[((size_t)g * N + c) * 2];
        s2 += part[((size_t)g * N + c) * 2 + 1];
    }
    float invB = 1.f / (float)Brows;
    float mean = s * invB;
    float var  = s2 * invB - mean * mean;
    float rstd = rsqrtf(var + 1e-5f);
    float sc = gamma[c] * rstd;
    scale[c] = sc;
    shift[c] = beta[c] - mean * sc;
}

__global__ __launch_bounds__(256) void bn_apply_f16(
    const float* __restrict__ Y, const float* __restrict__ scale,
    const float* __restrict__ shift, _Float16* __restrict__ oh,
    _Float16* __restrict__ ol, int total, int N, int act)
{
    int idx = blockIdx.x * 256 + threadIdx.x;
    int i4 = idx * 4;
    if (i4 >= total) return;
    float4 y = *(const float4*)(Y + i4);
    int c = i4 % N;
    float4 sc = *(const float4*)(scale + c);
    float4 sh = *(const float4*)(shift + c);
    float r[4];
    r[0] = y.x * sc.x + sh.x;
    r[1] = y.y * sc.y + sh.y;
    r[2] = y.z * sc.z + sh.z;
    r[3] = y.w * sc.w + sh.w;
    #pragma unroll
    for (int q = 0; q < 4; ++q) {
        if (act == ACT_RELU) r[q] = fmaxf(r[q], 0.f);
        else if (act == ACT_LEAKY) r[q] = (r[q] >= 0.f) ? r[q] : 0.01f * r[q];
    }
    f16x4 h;
    #pragma unroll
    for (int q = 0; q < 4; ++q) h[q] = (_Float16)r[q];
    ((f16x4*)oh)[idx] = h;
    if (ol) {
        f16x4 l;
        #pragma unroll
        for (int q = 0; q < 4; ++q) l[q] = (_Float16)(r[q] - (float)h[q]);
        ((f16x4*)ol)[idx] = l;
    }
}

// ============ Gumbel subset scan v4 (best measured: 92us, VGPR 40) ===========
// 256 thr (4 waves) per row; 8 elems/lane; linear W-space; SGPR-hoisted
// uniforms; stale-max refresh every 4th iter; sum-only 6-shfl reduce otherwise.
__global__ __launch_bounds__(256) void gumbel_scan(
    const float* __restrict__ WLg, const float* __restrict__ U,
    const float* __restrict__ X, _Float16* __restrict__ XM)
{
    const int row = blockIdx.x;
    const int t = threadIdx.x, wv = t >> 6, lane = t & 63;
    const float* wrow = WLg + (size_t)row * D_DIM + 8 * t;
    const float* urow = U + (size_t)row * D_DIM + 8 * t;
    const float* xrow = X + (size_t)row * D_DIM + 8 * t;
    _Float16* xmrow = XM + (size_t)row * D_DIM + 8 * t;

    const float L2E = 1.4426950408889634f;
    const float LOG2LN2 = -0.5287663729448977f;

    __shared__ f32x2 sLS[2][4];
    __shared__ float sM0[4];

    f32x2 W2[4], e2[4], acc2[4];

    auto mkW = [&](float wl, float uu) -> float {
        float u = fmaf(uu, 1.0f - 1e-10f, 1e-10f);
        float tl = -__builtin_amdgcn_logf(u);
        return __builtin_amdgcn_exp2f(fmaf(wl, L2E, __builtin_amdgcn_logf(tl) + LOG2LN2));
    };

    {
        float4 ua = *(const float4*)urow, ub = *(const float4*)(urow + 4);
        float4 wa = *(const float4*)wrow, wb = *(const float4*)(wrow + 4);
        W2[0] = f32x2{mkW(wa.x, ua.x), mkW(wa.y, ua.y)};
        W2[1] = f32x2{mkW(wa.z, ua.z), mkW(wa.w, ua.w)};
        W2[2] = f32x2{mkW(wb.x, ub.x), mkW(wb.y, ub.y)};
        W2[3] = f32x2{mkW(wb.z, ub.z), mkW(wb.w, ub.w)};
    }
    #pragma unroll
    for (int j = 0; j < 4; ++j) {
        e2[j] = f32x2{0.f, 0.f};
        acc2[j] = f32x2{0.f, 0.f};
    }

    float rm_s;
    {
        float lm = 0.f;
        #pragma unroll
        for (int j = 0; j < 4; ++j)
            lm = fmaxf(lm, fmaxf(W2[j].x, W2[j].y));
        #pragma unroll
        for (int off = 32; off; off >>= 1)
            lm = fmaxf(lm, __shfl_xor(lm, off));
        if (lane == 0) sM0[wv] = lm;
        __syncthreads();
        float m = fmaxf(fmaxf(sM0[0], sM0[1]), fmaxf(sM0[2], sM0[3]));
        rm_s = rfl(__builtin_amdgcn_rcpf(m));
    }

    float inv_s = 0.f;
    int gi = 0;

    auto iterate = [&](bool refresh) {
        const int p = gi & 1;
        ++gi;
        f32x2 lmv = f32x2{0.f, 0.f}, sv = f32x2{0.f, 0.f};
        #pragma unroll
        for (int j = 0; j < 4; ++j) {
            acc2[j].x = fmaf(e2[j].x, inv_s, acc2[j].x);
            acc2[j].y = fmaf(e2[j].y, inv_s, acc2[j].y);
            f32x2 msk;
            msk.x = fmaxf(fmaf(-e2[j].x, inv_s, 1.0f), 1e-10f);
            msk.y = fmaxf(fmaf(-e2[j].y, inv_s, 1.0f), 1e-10f);
            f32x2 Wn = W2[j] * msk;
            W2[j] = Wn;
            f32x2 r;
            r.x = Wn.x * rm_s;
            r.y = Wn.y * rm_s;
            f32x2 q2 = r * r;
            f32x2 q4 = q2 * q2;
            f32x2 q8 = q4 * q4;
            f32x2 ee = q8 * q2;
            e2[j] = ee;
            sv += ee;
            if (refresh) {
                lmv.x = fmaxf(lmv.x, Wn.x);
                lmv.y = fmaxf(lmv.y, Wn.y);
            }
        }
        float s = sv.x + sv.y;
        if (refresh) {
            float lm = fmaxf(lmv.x, lmv.y);
            #pragma unroll
            for (int off = 32; off; off >>= 1) {
                s += __shfl_xor(s, off);
                lm = fmaxf(lm, __shfl_xor(lm, off));
            }
            if (lane == 0) sLS[p][wv] = f32x2{lm, s};
            __syncthreads();
            f32x2 r0 = sLS[p][0], r1 = sLS[p][1], r2 = sLS[p][2], r3 = sLS[p][3];
            float m = fmaxf(fmaxf(r0.x, r1.x), fmaxf(r2.x, r3.x));
            float st = (r0.y + r1.y) + (r2.y + r3.y);
            rm_s = rfl(__builtin_amdgcn_rcpf(m));
            inv_s = rfl(__builtin_amdgcn_rcpf(st));
        } else {
            #pragma unroll
            for (int off = 32; off; off >>= 1)
                s += __shfl_xor(s, off);
            if (lane == 0) sLS[p][wv].y = s;
            __syncthreads();
            float st = (sLS[p][0].y + sLS[p][1].y) + (sLS[p][2].y + sLS[p][3].y);
            inv_s = rfl(__builtin_amdgcn_rcpf(st));
        }
    };

    for (int ot = 0; ot < 16; ++ot) {
        iterate(false);
        iterate(false);
        iterate(false);
        iterate(true);
    }

    {
        float4 xa = *(const float4*)xrow, xb = *(const float4*)(xrow + 4);
        f32x2 a0, a1, a2, a3;
        a0.x = fmaf(e2[0].x, inv_s, acc2[0].x); a0.y = fmaf(e2[0].y, inv_s, acc2[0].y);
        a1.x = fmaf(e2[1].x, inv_s, acc2[1].x); a1.y = fmaf(e2[1].y, inv_s, acc2[1].y);
        a2.x = fmaf(e2[2].x, inv_s, acc2[2].x); a2.y = fmaf(e2[2].y, inv_s, acc2[2].y);
        a3.x = fmaf(e2[3].x, inv_s, acc2[3].x); a3.y = fmaf(e2[3].y, inv_s, acc2[3].y);
        f16x8 o;
        o[0] = (_Float16)(xa.x * a0.x);
        o[1] = (_Float16)(xa.y * a0.y);
        o[2] = (_Float16)(xa.z * a1.x);
        o[3] = (_Float16)(xa.w * a1.y);
        o[4] = (_Float16)(xb.x * a2.x);
        o[5] = (_Float16)(xb.y * a2.y);
        o[6] = (_Float16)(xb.z * a3.x);
        o[7] = (_Float16)(xb.w * a3.y);
        *(f16x8*)xmrow = o;
    }
}

extern "C" void kernel_launch(void* const* d_in, const int* in_sizes, int n_in,
                              void* d_out, int out_size, void* d_ws, size_t ws_size,
                              hipStream_t stream) {
    const float* x        = (const float*)d_in[0];
    const float* u_gumbel = (const float*)d_in[1];
    const float* eps      = (const float*)d_in[2];
    const float* wc_w1    = (const float*)d_in[3];
    const float* wc_b1    = (const float*)d_in[4];
    const float* wc_g     = (const float*)d_in[5];
    const float* wc_beta  = (const float*)d_in[6];
    const float* wc_w2    = (const float*)d_in[7];
    const float* wc_b2    = (const float*)d_in[8];
    const float* enc_w1   = (const float*)d_in[9];
    const float* enc_b1   = (const float*)d_in[10];
    const float* enc_g1   = (const float*)d_in[11];
    const float* enc_beta1= (const float*)d_in[12];
    const float* enc_w2   = (const float*)d_in[13];
    const float* enc_b2   = (const float*)d_in[14];
    const float* enc_g2   = (const float*)d_in[15];
    const float* enc_beta2= (const float*)d_in[16];
    const float* enc_w3   = (const float*)d_in[17];
    const float* enc_b3   = (const float*)d_in[18];
    const float* enc_g3   = (const float*)d_in[19];
    const float* enc_beta3= (const float*)d_in[20];
    const float* fc21_w   = (const float*)d_in[21];
    const float* fc21_b   = (const float*)d_in[22];
    const float* fc22_w   = (const float*)d_in[23];
    const float* fc22_b   = (const float*)d_in[24];
    const float* fc3_w    = (const float*)d_in[25];
    const float* fc3_b    = (const float*)d_in[26];
    const float* fc3_g    = (const float*)d_in[27];
    const float* fc3_beta = (const float*)d_in[28];
    const float* fc4_w    = (const float*)d_in[29];
    const float* fc4_b    = (const float*)d_in[30];

    float* out   = (float*)d_out;
    float* mu_x  = out;
    float* mu    = out + (size_t)B_DIM * D_DIM;
    float* lv    = mu + (size_t)B_DIM * Z_DIM;

    const size_t F1M = 1u << 20;
    float* wsf = (float*)d_ws;
    float*     P_WL  = wsf;
    _Float16*  xh    = (_Float16*)(wsf + 4 * F1M);
    _Float16*  xl    = (_Float16*)(wsf + 6 * F1M);
    _Float16*  xm16  = (_Float16*)(wsf + 4 * F1M);
    float*     Yb    = wsf + 6 * F1M;
    _Float16*  a2    = (_Float16*)(wsf + 8 * F1M);
    _Float16*  a3    = (_Float16*)(wsf + 9 * F1M);
    _Float16*  a4    = (_Float16*)(wsf + 9 * F1M + F1M / 2);
    _Float16*  zb16  = (_Float16*)(wsf + 10 * F1M);
    _Float16*  a5    = (_Float16*)(wsf + 10 * F1M + F1M / 2);
    float*     Hbuf  = wsf + 11 * F1M;
    _Float16*  Hh    = (_Float16*)(wsf + 12 * F1M);
    _Float16*  Hl    = (_Float16*)(wsf + 12 * F1M + F1M / 2);
    _Float16*  w1th  = (_Float16*)(wsf + 13 * F1M);
    _Float16*  w1tl  = (_Float16*)(wsf + 13 * F1M + F1M / 2);
    _Float16*  w2th  = (_Float16*)(wsf + 14 * F1M);
    _Float16*  w2tl  = (_Float16*)(wsf + 14 * F1M + F1M / 2);
    _Float16*  e1t   = (_Float16*)(wsf + 15 * F1M);
    _Float16*  e2t   = (_Float16*)(wsf + 16 * F1M);
    _Float16*  e3t   = (_Float16*)(wsf + 16 * F1M + F1M / 4);
    _Float16*  f21t  = (_Float16*)(wsf + 16 * F1M + 3 * (F1M / 8));
    _Float16*  f22t  = (_Float16*)(wsf + 16 * F1M + 4 * (F1M / 8));  // contiguous after f21t
    _Float16*  f3t   = (_Float16*)(wsf + 16 * F1M + 5 * (F1M / 8));
    _Float16*  f4t   = (_Float16*)(wsf + 16 * F1M + 6 * (F1M / 8));
    float*     bnp   = wsf + 17 * F1M + F1M / 4;
    float*     scale = bnp + 131072;
    float*     shift = scale + 2048;

    const int G = 64;

    auto gemm3 = [&](const _Float16* Ah, const _Float16* Al,
                     const _Float16* Bh, const _Float16* Bl,
                     const float* b, float* C, float* part,
                     int N, int K, int SK) {
        dim3 grid((N + 63) / 64, B_DIM / 128, SK);
        gemm_f16<128, 64, 3, 32><<<grid, 256, 0, stream>>>(Ah, Al, Bh, Bl, b, C, part,
                                                           B_DIM, N, K, ACT_NONE, K / SK);
    };
    auto gemm1 = [&](const _Float16* Ah, const _Float16* Bh,
                     const float* b, float* C, float* part,
                     int N, int K, int act, int SK) {
        dim3 grid((N + 63) / 64, B_DIM / 128, SK);
        gemm_f16<128, 64, 1, 64><<<grid, 256, 0, stream>>>(Ah, nullptr, Bh, nullptr, b, C,
                                                           part, B_DIM, N, K, act, K / SK);
    };
    auto bnFromParts = [&](const float* part, int S, const float* b,
                           const float* g_, const float* beta_,
                           float* Y, _Float16* oh, _Float16* ol, int N, int act) {
        dim3 gp(N / 64, G);
        reduce_stats<<<gp, 256, 0, stream>>>(part, S, B_DIM, N, B_DIM / G, b, Y, bnp);
        colstats_final<<<(N + 255) / 256, 256, 0, stream>>>(bnp, G, N, B_DIM, g_, beta_, scale, shift);
        int total = B_DIM * N;
        bn_apply_f16<<<(total / 4 + 255) / 256, 256, 0, stream>>>(Y, scale, shift, oh, ol, total, N, act);
    };
    auto cvtw = [&](const float* in, _Float16* oh, _Float16* ol, int K, int N, int Kp, int Np) {
        dim3 grid(Kp / 32, Np / 32);
        cvt_w_t<<<grid, 256, 0, stream>>>(in, oh, ol, K, N, Kp);
    };

    // ---- converts ----
    cvt_split_x<<<4096, 256, 0, stream>>>(x, xh, xl, B_DIM * D_DIM / 4);
    cvtw(wc_w1, w1th, w1tl, 2048, 512, 2048, 512);
    cvtw(wc_w2, w2th, w2tl, 512, 2048, 512, 2048);
    cvtw(enc_w1, e1t, nullptr, 2048, 1024, 2048, 1024);
    cvtw(enc_w2, e2t, nullptr, 1024, 512, 1024, 512);
    cvtw(enc_w3, e3t, nullptr, 512, 512, 512, 512);
    cvtw(fc21_w, f21t, nullptr, 512, 500, 512, 512);
    cvtw(fc22_w, f22t, nullptr, 512, 500, 512, 512);
    cvtw(fc3_w, f3t, nullptr, 500, 512, 512, 512);
    cvtw(fc4_w, f4t, nullptr, 512, 2048, 512, 2048);

    // ---- weight_creator ----
    gemm3(xh, xl, w1th, w1tl, nullptr, nullptr, P_WL, 512, 2048, 4);
    bnFromParts(P_WL, 4, wc_b1, wc_g, wc_beta, Hbuf, Hh, Hl, 512, ACT_RELU);
    gemm3(Hh, Hl, w2th, w2tl, wc_b2, P_WL, nullptr, 2048, 512, 1);  // -> WL

    // ---- gumbel scan: WL -> xm16 (f16), block (4 waves) per row ----
    gumbel_scan<<<B_DIM, 256, 0, stream>>>(P_WL, u_gumbel, x, xm16);

    // ---- encoder ----
    gemm1(xm16, e1t, nullptr, nullptr, P_WL, 1024, 2048, ACT_NONE, 2);
    bnFromParts(P_WL, 2, enc_b1, enc_g1, enc_beta1, Yb, a2, nullptr, 1024, ACT_LEAKY);
    gemm1(a2, e2t, nullptr, nullptr, P_WL, 512, 1024, ACT_NONE, 4);
    bnFromParts(P_WL, 4, enc_b2, enc_g2, enc_beta2, Yb, a3, nullptr, 512, ACT_LEAKY);
    gemm1(a3, e3t, nullptr, nullptr, P_WL, 512, 512, ACT_NONE, 4);
    bnFromParts(P_WL, 4, enc_b3, enc_g3, enc_beta3, Yb, a4, nullptr, 512, ACT_LEAKY);

    // ---- heads: combined GEMM + fused reduce/reparam (mu, lv, zb16) ----
    gemm1(a4, f21t, nullptr, nullptr, P_WL, 1024, 512, ACT_NONE, 4);
    reduce_heads_z<<<(B_DIM * 512 + 255) / 256, 256, 0, stream>>>(
        P_WL, 4, fc21_b, fc22_b, eps, mu, lv, zb16);

    // ---- decoder ----
    gemm1(zb16, f3t, nullptr, nullptr, P_WL, 512, 512, ACT_NONE, 4);
    bnFromParts(P_WL, 4, fc3_b, fc3_g, fc3_beta, Yb, a5, nullptr, 512, ACT_LEAKY);
    gemm1(a5, f4t, fc4_b, mu_x, nullptr, 2048, 512, ACT_SIGMOID, 1);
}

// Round 20
// 393.805 us; speedup vs baseline: 1.0970x; 1.0602x over previous
//
#include <hip/hip_runtime.h>
#include <hip/hip_bf16.h>
#include <math.h>

#define B_DIM 2048
#define D_DIM 2048
#define H_DIM 512
#define Z_DIM 500

#define ACT_NONE 0
#define ACT_RELU 1
#define ACT_SIGMOID 2
#define ACT_LEAKY 3

typedef __attribute__((ext_vector_type(8))) _Float16 f16x8;
typedef __attribute__((ext_vector_type(4))) _Float16 f16x4;
typedef __attribute__((ext_vector_type(4))) float f32x4;
typedef __attribute__((ext_vector_type(2))) float f32x2;

__device__ __forceinline__ float rfl(float x) {
    return __uint_as_float(__builtin_amdgcn_readfirstlane(__float_as_uint(x)));
}

// ============ MFMA f16 GEMM, 128x64 tile, double-buffered, split-K ==========
// TERMS=3: 3-term split-f16 (fp32-class), BK=32, f32 partials.
// TERMS=1: plain f16, BK=64, f16 partials (outputs are f16-class anyway).
template<int BM, int BN, int TERMS, int BK, typename PT>
__global__ __launch_bounds__(256, 2) void gemm_f16(
    const _Float16* __restrict__ Ah_, const _Float16* __restrict__ Al_,
    const _Float16* __restrict__ Bh_, const _Float16* __restrict__ Bl_,
    const float* __restrict__ bias, float* __restrict__ C,
    PT* __restrict__ part, int M, int N, int K, int act, int Kc)
{
    constexpr int LDK = 40;
    constexpr int NPL = (TERMS == 3) ? 2 : 1;
    constexpr int NCH = BK / 32;
    constexpr int PSA = BM * LDK, PSB = BN * LDK;
    constexpr int CHUNK = NPL * (PSA + PSB);
    constexpr int BUF = NCH * CHUNK;
    constexpr int MT = BM / 32, NT = BN / 32;
    constexpr int CA = BM / 64, CB = BN / 64;
    __shared__ _Float16 smem[2 * BUF];

    const int t = threadIdx.x, lane = t & 63, wv = t >> 6;
    const int wrow = wv >> 1, wcol = wv & 1;
    const int row0 = blockIdx.y * BM, col0 = blockIdx.x * BN;
    const int ks = blockIdx.z * Kc;
    const int nk = Kc / BK;

    f16x8 rA[NCH][CA][NPL], rB[NCH][CB][NPL];

    auto gload = [&](int kt) {
        #pragma unroll
        for (int ch = 0; ch < NCH; ++ch) {
            int kc = kt + ch * 32;
            #pragma unroll
            for (int i = 0; i < CA; ++i) {
                int id = t + i * 256;
                int r = id >> 2, ko = (id & 3) * 8;
                size_t off = (size_t)(row0 + r) * K + kc + ko;
                rA[ch][i][0] = *(const f16x8*)(Ah_ + off);
                if constexpr (TERMS == 3) rA[ch][i][1] = *(const f16x8*)(Al_ + off);
            }
            #pragma unroll
            for (int i = 0; i < CB; ++i) {
                int id = t + i * 256;
                int r = id >> 2, ko = (id & 3) * 8;
                size_t off = (size_t)(col0 + r) * K + kc + ko;
                rB[ch][i][0] = *(const f16x8*)(Bh_ + off);
                if constexpr (TERMS == 3) rB[ch][i][1] = *(const f16x8*)(Bl_ + off);
            }
        }
    };
    auto cstore = [&](int b) {
        #pragma unroll
        for (int ch = 0; ch < NCH; ++ch) {
            _Float16* base = smem + b * BUF + ch * CHUNK;
            #pragma unroll
            for (int i = 0; i < CA; ++i) {
                int id = t + i * 256;
                int r = id >> 2, ko = (id & 3) * 8;
                *(f16x8*)&base[r * LDK + ko] = rA[ch][i][0];
                if constexpr (TERMS == 3) *(f16x8*)&base[PSA + r * LDK + ko] = rA[ch][i][1];
            }
            _Float16* bb = base + NPL * PSA;
            #pragma unroll
            for (int i = 0; i < CB; ++i) {
                int id = t + i * 256;
                int r = id >> 2, ko = (id & 3) * 8;
                *(f16x8*)&bb[r * LDK + ko] = rB[ch][i][0];
                if constexpr (TERMS == 3) *(f16x8*)&bb[PSB + r * LDK + ko] = rB[ch][i][1];
            }
        }
    };

    f32x4 acc[MT][NT];
    #pragma unroll
    for (int i = 0; i < MT; ++i)
        #pragma unroll
        for (int j = 0; j < NT; ++j) {
            f32x4 z = {0.f, 0.f, 0.f, 0.f};
            acc[i][j] = z;
        }

    const int q8 = (lane >> 4) * 8, fr = lane & 15;

    gload(ks);
    cstore(0);
    __syncthreads();

    for (int it = 0; it < nk; ++it) {
        int cur = it & 1;
        if (it + 1 < nk) gload(ks + (it + 1) * BK);

        #pragma unroll
        for (int ch = 0; ch < NCH; ++ch) {
            const _Float16* A0 = smem + cur * BUF + ch * CHUNK;
            const _Float16* A1 = A0 + PSA;
            const _Float16* B0 = A0 + NPL * PSA;
            const _Float16* B1 = B0 + PSB;
            f16x8 ah[MT], al[MT], bh[NT], bl[NT];
            #pragma unroll
            for (int i = 0; i < MT; ++i) {
                int r = wrow * (BM / 2) + i * 16 + fr;
                ah[i] = *(const f16x8*)&A0[r * LDK + q8];
                if constexpr (TERMS == 3) al[i] = *(const f16x8*)&A1[r * LDK + q8];
            }
            #pragma unroll
            for (int j = 0; j < NT; ++j) {
                int n = wcol * (BN / 2) + j * 16 + fr;
                bh[j] = *(const f16x8*)&B0[n * LDK + q8];
                if constexpr (TERMS == 3) bl[j] = *(const f16x8*)&B1[n * LDK + q8];
            }
            #pragma unroll
            for (int i = 0; i < MT; ++i)
                #pragma unroll
                for (int j = 0; j < NT; ++j) {
                    acc[i][j] = __builtin_amdgcn_mfma_f32_16x16x32_f16(ah[i], bh[j], acc[i][j], 0, 0, 0);
                    if constexpr (TERMS == 3) {
                        acc[i][j] = __builtin_amdgcn_mfma_f32_16x16x32_f16(ah[i], bl[j], acc[i][j], 0, 0, 0);
                        acc[i][j] = __builtin_amdgcn_mfma_f32_16x16x32_f16(al[i], bh[j], acc[i][j], 0, 0, 0);
                    }
                }
        }

        if (it + 1 < nk) cstore(cur ^ 1);
        __syncthreads();
    }

    const bool dopart = (gridDim.z > 1);
    if (dopart) {
        PT* dst = part + (size_t)blockIdx.z * M * N;
        #pragma unroll
        for (int i = 0; i < MT; ++i) {
            int rbase = row0 + wrow * (BM / 2) + i * 16 + (lane >> 4) * 4;
            #pragma unroll
            for (int j = 0; j < NT; ++j) {
                int c = col0 + wcol * (BN / 2) + j * 16 + (lane & 15);
                if (c < N) {
                    #pragma unroll
                    for (int q = 0; q < 4; ++q)
                        dst[(size_t)(rbase + q) * N + c] = (PT)acc[i][j][q];
                }
            }
        }
    } else {
        #pragma unroll
        for (int i = 0; i < MT; ++i) {
            int rbase = row0 + wrow * (BM / 2) + i * 16 + (lane >> 4) * 4;
            #pragma unroll
            for (int j = 0; j < NT; ++j) {
                int c = col0 + wcol * (BN / 2) + j * 16 + (lane & 15);
                if (c < N) {
                    float b = bias[c];
                    #pragma unroll
                    for (int q = 0; q < 4; ++q) {
                        float v = acc[i][j][q] + b;
                        if (act == ACT_SIGMOID)
                            v = 1.f / (1.f + __builtin_amdgcn_exp2f(-v * 1.44269504f));
                        C[(size_t)(rbase + q) * N + c] = v;
                    }
                }
            }
        }
    }
}

// ============ converters ============
__global__ __launch_bounds__(256) void cvt_split_x(
    const float* __restrict__ x, _Float16* __restrict__ xh,
    _Float16* __restrict__ xl, int n4)
{
    int i = blockIdx.x * 256 + threadIdx.x;
    if (i >= n4) return;
    float4 v = ((const float4*)x)[i];
    f16x4 h, l;
    h[0]=(_Float16)v.x; l[0]=(_Float16)(v.x-(float)h[0]);
    h[1]=(_Float16)v.y; l[1]=(_Float16)(v.y-(float)h[1]);
    h[2]=(_Float16)v.z; l[2]=(_Float16)(v.z-(float)h[2]);
    h[3]=(_Float16)v.w; l[3]=(_Float16)(v.w-(float)h[3]);
    ((f16x4*)xh)[i] = h;
    ((f16x4*)xl)[i] = l;
}

__global__ __launch_bounds__(256) void cvt_w_t(
    const float* __restrict__ in, _Float16* __restrict__ outh,
    _Float16* __restrict__ outl, int K, int N, int Kp)
{
    __shared__ float tile[32][33];
    const int t = threadIdx.x;
    const int tk0 = blockIdx.x * 32, tn0 = blockIdx.y * 32;
    const int lx = t & 31, ly = t >> 5;
    #pragma unroll
    for (int r = 0; r < 4; ++r) {
        int k = tk0 + ly + r * 8, n = tn0 + lx;
        tile[ly + r * 8][lx] = (k < K && n < N) ? in[(size_t)k * N + n] : 0.f;
    }
    __syncthreads();
    #pragma unroll
    for (int r = 0; r < 4; ++r) {
        int n = tn0 + ly + r * 8, k = tk0 + lx;
        float v = tile[lx][ly + r * 8];
        _Float16 h = (_Float16)v;
        outh[(size_t)n * Kp + k] = h;
        if (outl) outl[(size_t)n * Kp + k] = (_Float16)(v - (float)h);
    }
}

// ===== fused heads reduce + reparameterize (f16 partials) ====
__global__ __launch_bounds__(256) void reduce_heads_z(
    const _Float16* __restrict__ part, int S,
    const float* __restrict__ b21, const float* __restrict__ b22,
    const float* __restrict__ eps, float* __restrict__ mu,
    float* __restrict__ lv, _Float16* __restrict__ zb)
{
    int i = blockIdx.x * 256 + threadIdx.x;
    if (i >= B_DIM * 512) return;
    int row = i >> 9, c = i & 511;
    if (c < Z_DIM) {
        const size_t MN = (size_t)B_DIM * 1024;
        size_t ia = (size_t)row * 1024 + c;
        float sm = b21[c], sl = b22[c];
        for (int k = 0; k < S; ++k) {
            sm += (float)part[k * MN + ia];
            sl += (float)part[k * MN + ia + 512];
        }
        size_t o = (size_t)row * Z_DIM + c;
        mu[o] = sm;
        lv[o] = sl;
        const float HL2E = 0.7213475204444817f;  // 0.5*log2(e)
        zb[(size_t)row * 512 + c] =
            (_Float16)(sm + eps[o] * __builtin_amdgcn_exp2f(sl * HL2E));
    } else {
        zb[(size_t)row * 512 + c] = (_Float16)0.f;
    }
}

// ============ fused split-K reduce + bias + BN column stats ============
template<typename PT>
__global__ __launch_bounds__(256) void reduce_stats(
    const PT* __restrict__ part, int S, int Brows, int N, int rowsPerBlock,
    const float* __restrict__ bias, float* __restrict__ Y,
    float* __restrict__ statp)
{
    const int t = threadIdx.x;
    const int col = blockIdx.x * 64 + (t & 63);
    const int g = blockIdx.y;
    const int r0 = g * rowsPerBlock;
    const int r1 = min(r0 + rowsPerBlock, Brows);
    const size_t MN = (size_t)Brows * N;
    const float b = bias[col];
    float s = 0.f, s2 = 0.f;
    for (int r = r0 + (t >> 6); r < r1; r += 4) {
        float v = b;
        for (int k = 0; k < S; ++k) v += (float)part[k * MN + (size_t)r * N + col];
        Y[(size_t)r * N + col] = v;
        s += v;
        s2 += v * v;
    }
    __shared__ float ss[4][64], ss2[4][64];
    ss[t >> 6][t & 63] = s;
    ss2[t >> 6][t & 63] = s2;
    __syncthreads();
    if (t < 64) {
        s  = ss[0][t] + ss[1][t] + ss[2][t] + ss[3][t];
        s2 = ss2[0][t] + ss2[1][t] + ss2[2][t] + ss2[3][t];
        float* p = statp + ((size_t)g * N + col) * 2;
        p[0] = s;
        p[1] = s2;
    }
}

__global__ __launch_bounds__(256) void colstats_final(
    const float* __restrict__ part, int G, int N, int Brows,
    const float* __restrict__ gamma, const float* __restrict__ beta,
    float* __restrict__ scale, float* __restrict__ shift)
{
    int c = blockIdx.x * 256 + threadIdx.x;
    if (c >= N) return;
    float s = 0.f, s2 = 0.f;
    for (int g = 0; g < G; ++g) {
        s  += part[((size_t)g * N + c) * 2];
        s2 += part[((size_t)g * N + c) * 2 + 1];
    }
    float invB = 1.f / (float)Brows;
    float mean = s * invB;
    float var  = s2 * invB - mean * mean;
    float rstd = rsqrtf(var + 1e-5f);
    float sc = gamma[c] * rstd;
    scale[c] = sc;
    shift[c] = beta[c] - mean * sc;
}

__global__ __launch_bounds__(256) void bn_apply_f16(
    const float* __restrict__ Y, const float* __restrict__ scale,
    const float* __restrict__ shift, _Float16* __restrict__ oh,
    _Float16* __restrict__ ol, int total, int N, int act)
{
    int idx = blockIdx.x * 256 + threadIdx.x;
    int i4 = idx * 4;
    if (i4 >= total) return;
    float4 y = *(const float4*)(Y + i4);
    int c = i4 % N;
    float4 sc = *(const float4*)(scale + c);
    float4 sh = *(const float4*)(shift + c);
    float r[4];
    r[0] = y.x * sc.x + sh.x;
    r[1] = y.y * sc.y + sh.y;
    r[2] = y.z * sc.z + sh.z;
    r[3] = y.w * sc.w + sh.w;
    #pragma unroll
    for (int q = 0; q < 4; ++q) {
        if (act == ACT_RELU) r[q] = fmaxf(r[q], 0.f);
        else if (act == ACT_LEAKY) r[q] = (r[q] >= 0.f) ? r[q] : 0.01f * r[q];
    }
    f16x4 h;
    #pragma unroll
    for (int q = 0; q < 4; ++q) h[q] = (_Float16)r[q];
    ((f16x4*)oh)[idx] = h;
    if (ol) {
        f16x4 l;
        #pragma unroll
        for (int q = 0; q < 4; ++q) l[q] = (_Float16)(r[q] - (float)h[q]);
        ((f16x4*)ol)[idx] = l;
    }
}

// ============ Gumbel subset scan v4 (best measured: 92us, VGPR 40) ===========
__global__ __launch_bounds__(256) void gumbel_scan(
    const float* __restrict__ WLg, const float* __restrict__ U,
    const float* __restrict__ X, _Float16* __restrict__ XM)
{
    const int row = blockIdx.x;
    const int t = threadIdx.x, wv = t >> 6, lane = t & 63;
    const float* wrow = WLg + (size_t)row * D_DIM + 8 * t;
    const float* urow = U + (size_t)row * D_DIM + 8 * t;
    const float* xrow = X + (size_t)row * D_DIM + 8 * t;
    _Float16* xmrow = XM + (size_t)row * D_DIM + 8 * t;

    const float L2E = 1.4426950408889634f;
    const float LOG2LN2 = -0.5287663729448977f;

    __shared__ f32x2 sLS[2][4];
    __shared__ float sM0[4];

    f32x2 W2[4], e2[4], acc2[4];

    auto mkW = [&](float wl, float uu) -> float {
        float u = fmaf(uu, 1.0f - 1e-10f, 1e-10f);
        float tl = -__builtin_amdgcn_logf(u);
        return __builtin_amdgcn_exp2f(fmaf(wl, L2E, __builtin_amdgcn_logf(tl) + LOG2LN2));
    };

    {
        float4 ua = *(const float4*)urow, ub = *(const float4*)(urow + 4);
        float4 wa = *(const float4*)wrow, wb = *(const float4*)(wrow + 4);
        W2[0] = f32x2{mkW(wa.x, ua.x), mkW(wa.y, ua.y)};
        W2[1] = f32x2{mkW(wa.z, ua.z), mkW(wa.w, ua.w)};
        W2[2] = f32x2{mkW(wb.x, ub.x), mkW(wb.y, ub.y)};
        W2[3] = f32x2{mkW(wb.z, ub.z), mkW(wb.w, ub.w)};
    }
    #pragma unroll
    for (int j = 0; j < 4; ++j) {
        e2[j] = f32x2{0.f, 0.f};
        acc2[j] = f32x2{0.f, 0.f};
    }

    float rm_s;
    {
        float lm = 0.f;
        #pragma unroll
        for (int j = 0; j < 4; ++j)
            lm = fmaxf(lm, fmaxf(W2[j].x, W2[j].y));
        #pragma unroll
        for (int off = 32; off; off >>= 1)
            lm = fmaxf(lm, __shfl_xor(lm, off));
        if (lane == 0) sM0[wv] = lm;
        __syncthreads();
        float m = fmaxf(fmaxf(sM0[0], sM0[1]), fmaxf(sM0[2], sM0[3]));
        rm_s = rfl(__builtin_amdgcn_rcpf(m));
    }

    float inv_s = 0.f;
    int gi = 0;

    auto iterate = [&](bool refresh) {
        const int p = gi & 1;
        ++gi;
        f32x2 lmv = f32x2{0.f, 0.f}, sv = f32x2{0.f, 0.f};
        #pragma unroll
        for (int j = 0; j < 4; ++j) {
            acc2[j].x = fmaf(e2[j].x, inv_s, acc2[j].x);
            acc2[j].y = fmaf(e2[j].y, inv_s, acc2[j].y);
            f32x2 msk;
            msk.x = fmaxf(fmaf(-e2[j].x, inv_s, 1.0f), 1e-10f);
            msk.y = fmaxf(fmaf(-e2[j].y, inv_s, 1.0f), 1e-10f);
            f32x2 Wn = W2[j] * msk;
            W2[j] = Wn;
            f32x2 r;
            r.x = Wn.x * rm_s;
            r.y = Wn.y * rm_s;
            f32x2 q2 = r * r;
            f32x2 q4 = q2 * q2;
            f32x2 q8 = q4 * q4;
            f32x2 ee = q8 * q2;
            e2[j] = ee;
            sv += ee;
            if (refresh) {
                lmv.x = fmaxf(lmv.x, Wn.x);
                lmv.y = fmaxf(lmv.y, Wn.y);
            }
        }
        float s = sv.x + sv.y;
        if (refresh) {
            float lm = fmaxf(lmv.x, lmv.y);
            #pragma unroll
            for (int off = 32; off; off >>= 1) {
                s += __shfl_xor(s, off);
                lm = fmaxf(lm, __shfl_xor(lm, off));
            }
            if (lane == 0) sLS[p][wv] = f32x2{lm, s};
            __syncthreads();
            f32x2 r0 = sLS[p][0], r1 = sLS[p][1], r2 = sLS[p][2], r3 = sLS[p][3];
            float m = fmaxf(fmaxf(r0.x, r1.x), fmaxf(r2.x, r3.x));
            float st = (r0.y + r1.y) + (r2.y + r3.y);
            rm_s = rfl(__builtin_amdgcn_rcpf(m));
            inv_s = rfl(__builtin_amdgcn_rcpf(st));
        } else {
            #pragma unroll
            for (int off = 32; off; off >>= 1)
                s += __shfl_xor(s, off);
            if (lane == 0) sLS[p][wv].y = s;
            __syncthreads();
            float st = (sLS[p][0].y + sLS[p][1].y) + (sLS[p][2].y + sLS[p][3].y);
            inv_s = rfl(__builtin_amdgcn_rcpf(st));
        }
    };

    for (int ot = 0; ot < 16; ++ot) {
        iterate(false);
        iterate(false);
        iterate(false);
        iterate(true);
    }

    {
        float4 xa = *(const float4*)xrow, xb = *(const float4*)(xrow + 4);
        f32x2 a0, a1, a2, a3;
        a0.x = fmaf(e2[0].x, inv_s, acc2[0].x); a0.y = fmaf(e2[0].y, inv_s, acc2[0].y);
        a1.x = fmaf(e2[1].x, inv_s, acc2[1].x); a1.y = fmaf(e2[1].y, inv_s, acc2[1].y);
        a2.x = fmaf(e2[2].x, inv_s, acc2[2].x); a2.y = fmaf(e2[2].y, inv_s, acc2[2].y);
        a3.x = fmaf(e2[3].x, inv_s, acc2[3].x); a3.y = fmaf(e2[3].y, inv_s, acc2[3].y);
        f16x8 o;
        o[0] = (_Float16)(xa.x * a0.x);
        o[1] = (_Float16)(xa.y * a0.y);
        o[2] = (_Float16)(xa.z * a1.x);
        o[3] = (_Float16)(xa.w * a1.y);
        o[4] = (_Float16)(xb.x * a2.x);
        o[5] = (_Float16)(xb.y * a2.y);
        o[6] = (_Float16)(xb.z * a3.x);
        o[7] = (_Float16)(xb.w * a3.y);
        *(f16x8*)xmrow = o;
    }
}

extern "C" void kernel_launch(void* const* d_in, const int* in_sizes, int n_in,
                              void* d_out, int out_size, void* d_ws, size_t ws_size,
                              hipStream_t stream) {
    const float* x        = (const float*)d_in[0];
    const float* u_gumbel = (const float*)d_in[1];
    const float* eps      = (const float*)d_in[2];
    const float* wc_w1    = (const float*)d_in[3];
    const float* wc_b1    = (const float*)d_in[4];
    const float* wc_g     = (const float*)d_in[5];
    const float* wc_beta  = (const float*)d_in[6];
    const float* wc_w2    = (const float*)d_in[7];
    const float* wc_b2    = (const float*)d_in[8];
    const float* enc_w1   = (const float*)d_in[9];
    const float* enc_b1   = (const float*)d_in[10];
    const float* enc_g1   = (const float*)d_in[11];
    const float* enc_beta1= (const float*)d_in[12];
    const float* enc_w2   = (const float*)d_in[13];
    const float* enc_b2   = (const float*)d_in[14];
    const float* enc_g2   = (const float*)d_in[15];
    const float* enc_beta2= (const float*)d_in[16];
    const float* enc_w3   = (const float*)d_in[17];
    const float* enc_b3   = (const float*)d_in[18];
    const float* enc_g3   = (const float*)d_in[19];
    const float* enc_beta3= (const float*)d_in[20];
    const float* fc21_w   = (const float*)d_in[21];
    const float* fc21_b   = (const float*)d_in[22];
    const float* fc22_w   = (const float*)d_in[23];
    const float* fc22_b   = (const float*)d_in[24];
    const float* fc3_w    = (const float*)d_in[25];
    const float* fc3_b    = (const float*)d_in[26];
    const float* fc3_g    = (const float*)d_in[27];
    const float* fc3_beta = (const float*)d_in[28];
    const float* fc4_w    = (const float*)d_in[29];
    const float* fc4_b    = (const float*)d_in[30];

    float* out   = (float*)d_out;
    float* mu_x  = out;
    float* mu    = out + (size_t)B_DIM * D_DIM;
    float* lv    = mu + (size_t)B_DIM * Z_DIM;

    const size_t F1M = 1u << 20;
    float* wsf = (float*)d_ws;
    float*     P_WL  = wsf;                          // f32 partials / WL
    _Float16*  P16   = (_Float16*)wsf;               // f16 partials (same region)
    _Float16*  xh    = (_Float16*)(wsf + 4 * F1M);
    _Float16*  xl    = (_Float16*)(wsf + 6 * F1M);
    _Float16*  xm16  = (_Float16*)(wsf + 4 * F1M);
    float*     Yb    = wsf + 6 * F1M;
    _Float16*  a2    = (_Float16*)(wsf + 8 * F1M);
    _Float16*  a3    = (_Float16*)(wsf + 9 * F1M);
    _Float16*  a4    = (_Float16*)(wsf + 9 * F1M + F1M / 2);
    _Float16*  zb16  = (_Float16*)(wsf + 10 * F1M);
    _Float16*  a5    = (_Float16*)(wsf + 10 * F1M + F1M / 2);
    float*     Hbuf  = wsf + 11 * F1M;
    _Float16*  Hh    = (_Float16*)(wsf + 12 * F1M);
    _Float16*  Hl    = (_Float16*)(wsf + 12 * F1M + F1M / 2);
    _Float16*  w1th  = (_Float16*)(wsf + 13 * F1M);
    _Float16*  w1tl  = (_Float16*)(wsf + 13 * F1M + F1M / 2);
    _Float16*  w2th  = (_Float16*)(wsf + 14 * F1M);
    _Float16*  w2tl  = (_Float16*)(wsf + 14 * F1M + F1M / 2);
    _Float16*  e1t   = (_Float16*)(wsf + 15 * F1M);
    _Float16*  e2t   = (_Float16*)(wsf + 16 * F1M);
    _Float16*  e3t   = (_Float16*)(wsf + 16 * F1M + F1M / 4);
    _Float16*  f21t  = (_Float16*)(wsf + 16 * F1M + 3 * (F1M / 8));
    _Float16*  f22t  = (_Float16*)(wsf + 16 * F1M + 4 * (F1M / 8));  // contiguous after f21t
    _Float16*  f3t   = (_Float16*)(wsf + 16 * F1M + 5 * (F1M / 8));
    _Float16*  f4t   = (_Float16*)(wsf + 16 * F1M + 6 * (F1M / 8));
    float*     bnp   = wsf + 17 * F1M + F1M / 4;
    float*     scale = bnp + 131072;
    float*     shift = scale + 2048;

    const int G = 64;

    auto gemm3 = [&](const _Float16* Ah, const _Float16* Al,
                     const _Float16* Bh, const _Float16* Bl,
                     const float* b, float* C, float* part,
                     int N, int K, int SK) {
        dim3 grid((N + 63) / 64, B_DIM / 128, SK);
        gemm_f16<128, 64, 3, 32, float><<<grid, 256, 0, stream>>>(
            Ah, Al, Bh, Bl, b, C, part, B_DIM, N, K, ACT_NONE, K / SK);
    };
    auto gemm1 = [&](const _Float16* Ah, const _Float16* Bh,
                     const float* b, float* C, _Float16* part,
                     int N, int K, int act, int SK) {
        dim3 grid((N + 63) / 64, B_DIM / 128, SK);
        gemm_f16<128, 64, 1, 64, _Float16><<<grid, 256, 0, stream>>>(
            Ah, nullptr, Bh, nullptr, b, C, part, B_DIM, N, K, act, K / SK);
    };
    auto bnFromParts32 = [&](const float* part, int S, const float* b,
                             const float* g_, const float* beta_,
                             float* Y, _Float16* oh, _Float16* ol, int N, int act) {
        dim3 gp(N / 64, G);
        reduce_stats<float><<<gp, 256, 0, stream>>>(part, S, B_DIM, N, B_DIM / G, b, Y, bnp);
        colstats_final<<<(N + 255) / 256, 256, 0, stream>>>(bnp, G, N, B_DIM, g_, beta_, scale, shift);
        int total = B_DIM * N;
        bn_apply_f16<<<(total / 4 + 255) / 256, 256, 0, stream>>>(Y, scale, shift, oh, ol, total, N, act);
    };
    auto bnFromParts16 = [&](const _Float16* part, int S, const float* b,
                             const float* g_, const float* beta_,
                             float* Y, _Float16* oh, _Float16* ol, int N, int act) {
        dim3 gp(N / 64, G);
        reduce_stats<_Float16><<<gp, 256, 0, stream>>>(part, S, B_DIM, N, B_DIM / G, b, Y, bnp);
        colstats_final<<<(N + 255) / 256, 256, 0, stream>>>(bnp, G, N, B_DIM, g_, beta_, scale, shift);
        int total = B_DIM * N;
        bn_apply_f16<<<(total / 4 + 255) / 256, 256, 0, stream>>>(Y, scale, shift, oh, ol, total, N, act);
    };
    auto cvtw = [&](const float* in, _Float16* oh, _Float16* ol, int K, int N, int Kp, int Np) {
        dim3 grid(Kp / 32, Np / 32);
        cvt_w_t<<<grid, 256, 0, stream>>>(in, oh, ol, K, N, Kp);
    };

    // ---- converts ----
    cvt_split_x<<<4096, 256, 0, stream>>>(x, xh, xl, B_DIM * D_DIM / 4);
    cvtw(wc_w1, w1th, w1tl, 2048, 512, 2048, 512);
    cvtw(wc_w2, w2th, w2tl, 512, 2048, 512, 2048);
    cvtw(enc_w1, e1t, nullptr, 2048, 1024, 2048, 1024);
    cvtw(enc_w2, e2t, nullptr, 1024, 512, 1024, 512);
    cvtw(enc_w3, e3t, nullptr, 512, 512, 512, 512);
    cvtw(fc21_w, f21t, nullptr, 512, 500, 512, 512);
    cvtw(fc22_w, f22t, nullptr, 512, 500, 512, 512);
    cvtw(fc3_w, f3t, nullptr, 500, 512, 512, 512);
    cvtw(fc4_w, f4t, nullptr, 512, 2048, 512, 2048);

    // ---- weight_creator (fp32-class path: f32 partials) ----
    gemm3(xh, xl, w1th, w1tl, nullptr, nullptr, P_WL, 512, 2048, 4);
    bnFromParts32(P_WL, 4, wc_b1, wc_g, wc_beta, Hbuf, Hh, Hl, 512, ACT_RELU);
    gemm3(Hh, Hl, w2th, w2tl, wc_b2, P_WL, nullptr, 2048, 512, 1);  // -> WL

    // ---- gumbel scan: WL -> xm16 (f16), block (4 waves) per row ----
    gumbel_scan<<<B_DIM, 256, 0, stream>>>(P_WL, u_gumbel, x, xm16);

    // ---- encoder (f16 partials) ----
    gemm1(xm16, e1t, nullptr, nullptr, P16, 1024, 2048, ACT_NONE, 2);
    bnFromParts16(P16, 2, enc_b1, enc_g1, enc_beta1, Yb, a2, nullptr, 1024, ACT_LEAKY);
    gemm1(a2, e2t, nullptr, nullptr, P16, 512, 1024, ACT_NONE, 4);
    bnFromParts16(P16, 4, enc_b2, enc_g2, enc_beta2, Yb, a3, nullptr, 512, ACT_LEAKY);
    gemm1(a3, e3t, nullptr, nullptr, P16, 512, 512, ACT_NONE, 4);
    bnFromParts16(P16, 4, enc_b3, enc_g3, enc_beta3, Yb, a4, nullptr, 512, ACT_LEAKY);

    // ---- heads: combined GEMM + fused reduce/reparam (mu, lv, zb16) ----
    gemm1(a4, f21t, nullptr, nullptr, P16, 1024, 512, ACT_NONE, 4);
    reduce_heads_z<<<(B_DIM * 512 + 255) / 256, 256, 0, stream>>>(
        P16, 4, fc21_b, fc22_b, eps, mu, lv, zb16);

    // ---- decoder ----
    gemm1(zb16, f3t, nullptr, nullptr, P16, 512, 512, ACT_NONE, 4);
    bnFromParts16(P16, 4, fc3_b, fc3_g, fc3_beta, Yb, a5, nullptr, 512, ACT_LEAKY);
    gemm1(a5, f4t, fc4_b, mu_x, nullptr, 2048, 512, ACT_SIGMOID, 1);
}

// Round 21
// 393.304 us; speedup vs baseline: 1.0984x; 1.0013x over previous
//
#include <hip/hip_runtime.h>
#include <hip/hip_bf16.h>
#include <math.h>

#define B_DIM 2048
#define D_DIM 2048
#define H_DIM 512
#define Z_DIM 500

#define ACT_NONE 0
#define ACT_RELU 1
#define ACT_SIGMOID 2
#define ACT_LEAKY 3

typedef __attribute__((ext_vector_type(8))) _Float16 f16x8;
typedef __attribute__((ext_vector_type(4))) _Float16 f16x4;
typedef __attribute__((ext_vector_type(4))) float f32x4;
typedef __attribute__((ext_vector_type(2))) float f32x2;

__device__ __forceinline__ float rfl(float x) {
    return __uint_as_float(__builtin_amdgcn_readfirstlane(__float_as_uint(x)));
}

// ============ MFMA f16 GEMM, 128x64 tile, double-buffered, split-K ==========
// TERMS=3: 3-term split-f16 (fp32-class), BK=32, f32 partials.
// TERMS=1: plain f16, BK=64, f16 partials.
template<int BM, int BN, int TERMS, int BK, typename PT>
__global__ __launch_bounds__(256, 2) void gemm_f16(
    const _Float16* __restrict__ Ah_, const _Float16* __restrict__ Al_,
    const _Float16* __restrict__ Bh_, const _Float16* __restrict__ Bl_,
    const float* __restrict__ bias, float* __restrict__ C,
    PT* __restrict__ part, int M, int N, int K, int act, int Kc)
{
    constexpr int LDK = 40;
    constexpr int NPL = (TERMS == 3) ? 2 : 1;
    constexpr int NCH = BK / 32;
    constexpr int PSA = BM * LDK, PSB = BN * LDK;
    constexpr int CHUNK = NPL * (PSA + PSB);
    constexpr int BUF = NCH * CHUNK;
    constexpr int MT = BM / 32, NT = BN / 32;
    constexpr int CA = BM / 64, CB = BN / 64;
    __shared__ _Float16 smem[2 * BUF];

    const int t = threadIdx.x, lane = t & 63, wv = t >> 6;
    const int wrow = wv >> 1, wcol = wv & 1;
    const int row0 = blockIdx.y * BM, col0 = blockIdx.x * BN;
    const int ks = blockIdx.z * Kc;
    const int nk = Kc / BK;

    f16x8 rA[NCH][CA][NPL], rB[NCH][CB][NPL];

    auto gload = [&](int kt) {
        #pragma unroll
        for (int ch = 0; ch < NCH; ++ch) {
            int kc = kt + ch * 32;
            #pragma unroll
            for (int i = 0; i < CA; ++i) {
                int id = t + i * 256;
                int r = id >> 2, ko = (id & 3) * 8;
                size_t off = (size_t)(row0 + r) * K + kc + ko;
                rA[ch][i][0] = *(const f16x8*)(Ah_ + off);
                if constexpr (TERMS == 3) rA[ch][i][1] = *(const f16x8*)(Al_ + off);
            }
            #pragma unroll
            for (int i = 0; i < CB; ++i) {
                int id = t + i * 256;
                int r = id >> 2, ko = (id & 3) * 8;
                size_t off = (size_t)(col0 + r) * K + kc + ko;
                rB[ch][i][0] = *(const f16x8*)(Bh_ + off);
                if constexpr (TERMS == 3) rB[ch][i][1] = *(const f16x8*)(Bl_ + off);
            }
        }
    };
    auto cstore = [&](int b) {
        #pragma unroll
        for (int ch = 0; ch < NCH; ++ch) {
            _Float16* base = smem + b * BUF + ch * CHUNK;
            #pragma unroll
            for (int i = 0; i < CA; ++i) {
                int id = t + i * 256;
                int r = id >> 2, ko = (id & 3) * 8;
                *(f16x8*)&base[r * LDK + ko] = rA[ch][i][0];
                if constexpr (TERMS == 3) *(f16x8*)&base[PSA + r * LDK + ko] = rA[ch][i][1];
            }
            _Float16* bb = base + NPL * PSA;
            #pragma unroll
            for (int i = 0; i < CB; ++i) {
                int id = t + i * 256;
                int r = id >> 2, ko = (id & 3) * 8;
                *(f16x8*)&bb[r * LDK + ko] = rB[ch][i][0];
                if constexpr (TERMS == 3) *(f16x8*)&bb[PSB + r * LDK + ko] = rB[ch][i][1];
            }
        }
    };

    f32x4 acc[MT][NT];
    #pragma unroll
    for (int i = 0; i < MT; ++i)
        #pragma unroll
        for (int j = 0; j < NT; ++j) {
            f32x4 z = {0.f, 0.f, 0.f, 0.f};
            acc[i][j] = z;
        }

    const int q8 = (lane >> 4) * 8, fr = lane & 15;

    gload(ks);
    cstore(0);
    __syncthreads();

    for (int it = 0; it < nk; ++it) {
        int cur = it & 1;
        if (it + 1 < nk) gload(ks + (it + 1) * BK);

        #pragma unroll
        for (int ch = 0; ch < NCH; ++ch) {
            const _Float16* A0 = smem + cur * BUF + ch * CHUNK;
            const _Float16* A1 = A0 + PSA;
            const _Float16* B0 = A0 + NPL * PSA;
            const _Float16* B1 = B0 + PSB;
            f16x8 ah[MT], al[MT], bh[NT], bl[NT];
            #pragma unroll
            for (int i = 0; i < MT; ++i) {
                int r = wrow * (BM / 2) + i * 16 + fr;
                ah[i] = *(const f16x8*)&A0[r * LDK + q8];
                if constexpr (TERMS == 3) al[i] = *(const f16x8*)&A1[r * LDK + q8];
            }
            #pragma unroll
            for (int j = 0; j < NT; ++j) {
                int n = wcol * (BN / 2) + j * 16 + fr;
                bh[j] = *(const f16x8*)&B0[n * LDK + q8];
                if constexpr (TERMS == 3) bl[j] = *(const f16x8*)&B1[n * LDK + q8];
            }
            #pragma unroll
            for (int i = 0; i < MT; ++i)
                #pragma unroll
                for (int j = 0; j < NT; ++j) {
                    acc[i][j] = __builtin_amdgcn_mfma_f32_16x16x32_f16(ah[i], bh[j], acc[i][j], 0, 0, 0);
                    if constexpr (TERMS == 3) {
                        acc[i][j] = __builtin_amdgcn_mfma_f32_16x16x32_f16(ah[i], bl[j], acc[i][j], 0, 0, 0);
                        acc[i][j] = __builtin_amdgcn_mfma_f32_16x16x32_f16(al[i], bh[j], acc[i][j], 0, 0, 0);
                    }
                }
        }

        if (it + 1 < nk) cstore(cur ^ 1);
        __syncthreads();
    }

    const bool dopart = (gridDim.z > 1);
    if (dopart) {
        PT* dst = part + (size_t)blockIdx.z * M * N;
        #pragma unroll
        for (int i = 0; i < MT; ++i) {
            int rbase = row0 + wrow * (BM / 2) + i * 16 + (lane >> 4) * 4;
            #pragma unroll
            for (int j = 0; j < NT; ++j) {
                int c = col0 + wcol * (BN / 2) + j * 16 + (lane & 15);
                if (c < N) {
                    #pragma unroll
                    for (int q = 0; q < 4; ++q)
                        dst[(size_t)(rbase + q) * N + c] = (PT)acc[i][j][q];
                }
            }
        }
    } else {
        #pragma unroll
        for (int i = 0; i < MT; ++i) {
            int rbase = row0 + wrow * (BM / 2) + i * 16 + (lane >> 4) * 4;
            #pragma unroll
            for (int j = 0; j < NT; ++j) {
                int c = col0 + wcol * (BN / 2) + j * 16 + (lane & 15);
                if (c < N) {
                    float b = bias[c];
                    #pragma unroll
                    for (int q = 0; q < 4; ++q) {
                        float v = acc[i][j][q] + b;
                        if (act == ACT_SIGMOID)
                            v = 1.f / (1.f + __builtin_amdgcn_exp2f(-v * 1.44269504f));
                        C[(size_t)(rbase + q) * N + c] = v;
                    }
                }
            }
        }
    }
}

// ============ converters ============
__global__ __launch_bounds__(256) void cvt_split_x(
    const float* __restrict__ x, _Float16* __restrict__ xh,
    _Float16* __restrict__ xl, int n4)
{
    int i = blockIdx.x * 256 + threadIdx.x;
    if (i >= n4) return;
    float4 v = ((const float4*)x)[i];
    f16x4 h, l;
    h[0]=(_Float16)v.x; l[0]=(_Float16)(v.x-(float)h[0]);
    h[1]=(_Float16)v.y; l[1]=(_Float16)(v.y-(float)h[1]);
    h[2]=(_Float16)v.z; l[2]=(_Float16)(v.z-(float)h[2]);
    h[3]=(_Float16)v.w; l[3]=(_Float16)(v.w-(float)h[3]);
    ((f16x4*)xh)[i] = h;
    ((f16x4*)xl)[i] = l;
}

__global__ __launch_bounds__(256) void cvt_w_t(
    const float* __restrict__ in, _Float16* __restrict__ outh,
    _Float16* __restrict__ outl, int K, int N, int Kp)
{
    __shared__ float tile[32][33];
    const int t = threadIdx.x;
    const int tk0 = blockIdx.x * 32, tn0 = blockIdx.y * 32;
    const int lx = t & 31, ly = t >> 5;
    #pragma unroll
    for (int r = 0; r < 4; ++r) {
        int k = tk0 + ly + r * 8, n = tn0 + lx;
        tile[ly + r * 8][lx] = (k < K && n < N) ? in[(size_t)k * N + n] : 0.f;
    }
    __syncthreads();
    #pragma unroll
    for (int r = 0; r < 4; ++r) {
        int n = tn0 + ly + r * 8, k = tk0 + lx;
        float v = tile[lx][ly + r * 8];
        _Float16 h = (_Float16)v;
        outh[(size_t)n * Kp + k] = h;
        if (outl) outl[(size_t)n * Kp + k] = (_Float16)(v - (float)h);
    }
}

// ===== fused heads reduce + reparameterize (f16 partials) ====
__global__ __launch_bounds__(256) void reduce_heads_z(
    const _Float16* __restrict__ part, int S,
    const float* __restrict__ b21, const float* __restrict__ b22,
    const float* __restrict__ eps, float* __restrict__ mu,
    float* __restrict__ lv, _Float16* __restrict__ zb)
{
    int i = blockIdx.x * 256 + threadIdx.x;
    if (i >= B_DIM * 512) return;
    int row = i >> 9, c = i & 511;
    if (c < Z_DIM) {
        const size_t MN = (size_t)B_DIM * 1024;
        size_t ia = (size_t)row * 1024 + c;
        float sm = b21[c], sl = b22[c];
        for (int k = 0; k < S; ++k) {
            sm += (float)part[k * MN + ia];
            sl += (float)part[k * MN + ia + 512];
        }
        size_t o = (size_t)row * Z_DIM + c;
        mu[o] = sm;
        lv[o] = sl;
        const float HL2E = 0.7213475204444817f;  // 0.5*log2(e)
        zb[(size_t)row * 512 + c] =
            (_Float16)(sm + eps[o] * __builtin_amdgcn_exp2f(sl * HL2E));
    } else {
        zb[(size_t)row * 512 + c] = (_Float16)0.f;
    }
}

// ============ fused split-K reduce + bias + BN column stats ============
// Y stored as YT (f16 on encoder/decoder paths; f32 on the fp32-class wc path).
// Stats computed from the ROUNDED value so stats and apply are self-consistent.
template<typename PT, typename YT>
__global__ __launch_bounds__(256) void reduce_stats(
    const PT* __restrict__ part, int S, int Brows, int N, int rowsPerBlock,
    const float* __restrict__ bias, YT* __restrict__ Y,
    float* __restrict__ statp)
{
    const int t = threadIdx.x;
    const int col = blockIdx.x * 64 + (t & 63);
    const int g = blockIdx.y;
    const int r0 = g * rowsPerBlock;
    const int r1 = min(r0 + rowsPerBlock, Brows);
    const size_t MN = (size_t)Brows * N;
    const float b = bias[col];
    float s = 0.f, s2 = 0.f;
    for (int r = r0 + (t >> 6); r < r1; r += 4) {
        float v = b;
        for (int k = 0; k < S; ++k) v += (float)part[k * MN + (size_t)r * N + col];
        YT vr = (YT)v;
        Y[(size_t)r * N + col] = vr;
        float vv = (float)vr;
        s += vv;
        s2 += vv * vv;
    }
    __shared__ float ss[4][64], ss2[4][64];
    ss[t >> 6][t & 63] = s;
    ss2[t >> 6][t & 63] = s2;
    __syncthreads();
    if (t < 64) {
        s  = ss[0][t] + ss[1][t] + ss[2][t] + ss[3][t];
        s2 = ss2[0][t] + ss2[1][t] + ss2[2][t] + ss2[3][t];
        float* p = statp + ((size_t)g * N + col) * 2;
        p[0] = s;
        p[1] = s2;
    }
}

__global__ __launch_bounds__(256) void colstats_final(
    const float* __restrict__ part, int G, int N, int Brows,
    const float* __restrict__ gamma, const float* __restrict__ beta,
    float* __restrict__ scale, float* __restrict__ shift)
{
    int c = blockIdx.x * 256 + threadIdx.x;
    if (c >= N) return;
    float s = 0.f, s2 = 0.f;
    for (int g = 0; g < G; ++g) {
        s  += part[((size_t)g * N + c) * 2];
        s2 += part[((size_t)g * N + c) * 2 + 1];
    }
    float invB = 1.f / (float)Brows;
    float mean = s * invB;
    float var  = s2 * invB - mean * mean;
    float rstd = rsqrtf(var + 1e-5f);
    float sc = gamma[c] * rstd;
    scale[c] = sc;
    shift[c] = beta[c] - mean * sc;
}

template<typename YT>
__global__ __launch_bounds__(256) void bn_apply_f16(
    const YT* __restrict__ Y, const float* __restrict__ scale,
    const float* __restrict__ shift, _Float16* __restrict__ oh,
    _Float16* __restrict__ ol, int total, int N, int act)
{
    int idx = blockIdx.x * 256 + threadIdx.x;
    int i4 = idx * 4;
    if (i4 >= total) return;
    float y[4];
    if constexpr (sizeof(YT) == 2) {
        f16x4 yv = *(const f16x4*)(Y + i4);
        y[0] = (float)yv[0]; y[1] = (float)yv[1];
        y[2] = (float)yv[2]; y[3] = (float)yv[3];
    } else {
        float4 yv = *(const float4*)(Y + i4);
        y[0] = yv.x; y[1] = yv.y; y[2] = yv.z; y[3] = yv.w;
    }
    int c = i4 % N;
    float4 sc = *(const float4*)(scale + c);
    float4 sh = *(const float4*)(shift + c);
    float r[4];
    r[0] = y[0] * sc.x + sh.x;
    r[1] = y[1] * sc.y + sh.y;
    r[2] = y[2] * sc.z + sh.z;
    r[3] = y[3] * sc.w + sh.w;
    #pragma unroll
    for (int q = 0; q < 4; ++q) {
        if (act == ACT_RELU) r[q] = fmaxf(r[q], 0.f);
        else if (act == ACT_LEAKY) r[q] = (r[q] >= 0.f) ? r[q] : 0.01f * r[q];
    }
    f16x4 h;
    #pragma unroll
    for (int q = 0; q < 4; ++q) h[q] = (_Float16)r[q];
    ((f16x4*)oh)[idx] = h;
    if (ol) {
        f16x4 l;
        #pragma unroll
        for (int q = 0; q < 4; ++q) l[q] = (_Float16)(r[q] - (float)h[q]);
        ((f16x4*)ol)[idx] = l;
    }
}

// ============ Gumbel subset scan v4 (best measured: 92us, VGPR 40) ===========
__global__ __launch_bounds__(256) void gumbel_scan(
    const float* __restrict__ WLg, const float* __restrict__ U,
    const float* __restrict__ X, _Float16* __restrict__ XM)
{
    const int row = blockIdx.x;
    const int t = threadIdx.x, wv = t >> 6, lane = t & 63;
    const float* wrow = WLg + (size_t)row * D_DIM + 8 * t;
    const float* urow = U + (size_t)row * D_DIM + 8 * t;
    const float* xrow = X + (size_t)row * D_DIM + 8 * t;
    _Float16* xmrow = XM + (size_t)row * D_DIM + 8 * t;

    const float L2E = 1.4426950408889634f;
    const float LOG2LN2 = -0.5287663729448977f;

    __shared__ f32x2 sLS[2][4];
    __shared__ float sM0[4];

    f32x2 W2[4], e2[4], acc2[4];

    auto mkW = [&](float wl, float uu) -> float {
        float u = fmaf(uu, 1.0f - 1e-10f, 1e-10f);
        float tl = -__builtin_amdgcn_logf(u);
        return __builtin_amdgcn_exp2f(fmaf(wl, L2E, __builtin_amdgcn_logf(tl) + LOG2LN2));
    };

    {
        float4 ua = *(const float4*)urow, ub = *(const float4*)(urow + 4);
        float4 wa = *(const float4*)wrow, wb = *(const float4*)(wrow + 4);
        W2[0] = f32x2{mkW(wa.x, ua.x), mkW(wa.y, ua.y)};
        W2[1] = f32x2{mkW(wa.z, ua.z), mkW(wa.w, ua.w)};
        W2[2] = f32x2{mkW(wb.x, ub.x), mkW(wb.y, ub.y)};
        W2[3] = f32x2{mkW(wb.z, ub.z), mkW(wb.w, ub.w)};
    }
    #pragma unroll
    for (int j = 0; j < 4; ++j) {
        e2[j] = f32x2{0.f, 0.f};
        acc2[j] = f32x2{0.f, 0.f};
    }

    float rm_s;
    {
        float lm = 0.f;
        #pragma unroll
        for (int j = 0; j < 4; ++j)
            lm = fmaxf(lm, fmaxf(W2[j].x, W2[j].y));
        #pragma unroll
        for (int off = 32; off; off >>= 1)
            lm = fmaxf(lm, __shfl_xor(lm, off));
        if (lane == 0) sM0[wv] = lm;
        __syncthreads();
        float m = fmaxf(fmaxf(sM0[0], sM0[1]), fmaxf(sM0[2], sM0[3]));
        rm_s = rfl(__builtin_amdgcn_rcpf(m));
    }

    float inv_s = 0.f;
    int gi = 0;

    auto iterate = [&](bool refresh) {
        const int p = gi & 1;
        ++gi;
        f32x2 lmv = f32x2{0.f, 0.f}, sv = f32x2{0.f, 0.f};
        #pragma unroll
        for (int j = 0; j < 4; ++j) {
            acc2[j].x = fmaf(e2[j].x, inv_s, acc2[j].x);
            acc2[j].y = fmaf(e2[j].y, inv_s, acc2[j].y);
            f32x2 msk;
            msk.x = fmaxf(fmaf(-e2[j].x, inv_s, 1.0f), 1e-10f);
            msk.y = fmaxf(fmaf(-e2[j].y, inv_s, 1.0f), 1e-10f);
            f32x2 Wn = W2[j] * msk;
            W2[j] = Wn;
            f32x2 r;
            r.x = Wn.x * rm_s;
            r.y = Wn.y * rm_s;
            f32x2 q2 = r * r;
            f32x2 q4 = q2 * q2;
            f32x2 q8 = q4 * q4;
            f32x2 ee = q8 * q2;
            e2[j] = ee;
            sv += ee;
            if (refresh) {
                lmv.x = fmaxf(lmv.x, Wn.x);
                lmv.y = fmaxf(lmv.y, Wn.y);
            }
        }
        float s = sv.x + sv.y;
        if (refresh) {
            float lm = fmaxf(lmv.x, lmv.y);
            #pragma unroll
            for (int off = 32; off; off >>= 1) {
                s += __shfl_xor(s, off);
                lm = fmaxf(lm, __shfl_xor(lm, off));
            }
            if (lane == 0) sLS[p][wv] = f32x2{lm, s};
            __syncthreads();
            f32x2 r0 = sLS[p][0], r1 = sLS[p][1], r2 = sLS[p][2], r3 = sLS[p][3];
            float m = fmaxf(fmaxf(r0.x, r1.x), fmaxf(r2.x, r3.x));
            float st = (r0.y + r1.y) + (r2.y + r3.y);
            rm_s = rfl(__builtin_amdgcn_rcpf(m));
            inv_s = rfl(__builtin_amdgcn_rcpf(st));
        } else {
            #pragma unroll
            for (int off = 32; off; off >>= 1)
                s += __shfl_xor(s, off);
            if (lane == 0) sLS[p][wv].y = s;
            __syncthreads();
            float st = (sLS[p][0].y + sLS[p][1].y) + (sLS[p][2].y + sLS[p][3].y);
            inv_s = rfl(__builtin_amdgcn_rcpf(st));
        }
    };

    for (int ot = 0; ot < 16; ++ot) {
        iterate(false);
        iterate(false);
        iterate(false);
        iterate(true);
    }

    {
        float4 xa = *(const float4*)xrow, xb = *(const float4*)(xrow + 4);
        f32x2 a0, a1, a2, a3;
        a0.x = fmaf(e2[0].x, inv_s, acc2[0].x); a0.y = fmaf(e2[0].y, inv_s, acc2[0].y);
        a1.x = fmaf(e2[1].x, inv_s, acc2[1].x); a1.y = fmaf(e2[1].y, inv_s, acc2[1].y);
        a2.x = fmaf(e2[2].x, inv_s, acc2[2].x); a2.y = fmaf(e2[2].y, inv_s, acc2[2].y);
        a3.x = fmaf(e2[3].x, inv_s, acc2[3].x); a3.y = fmaf(e2[3].y, inv_s, acc2[3].y);
        f16x8 o;
        o[0] = (_Float16)(xa.x * a0.x);
        o[1] = (_Float16)(xa.y * a0.y);
        o[2] = (_Float16)(xa.z * a1.x);
        o[3] = (_Float16)(xa.w * a1.y);
        o[4] = (_Float16)(xb.x * a2.x);
        o[5] = (_Float16)(xb.y * a2.y);
        o[6] = (_Float16)(xb.z * a3.x);
        o[7] = (_Float16)(xb.w * a3.y);
        *(f16x8*)xmrow = o;
    }
}

extern "C" void kernel_launch(void* const* d_in, const int* in_sizes, int n_in,
                              void* d_out, int out_size, void* d_ws, size_t ws_size,
                              hipStream_t stream) {
    const float* x        = (const float*)d_in[0];
    const float* u_gumbel = (const float*)d_in[1];
    const float* eps      = (const float*)d_in[2];
    const float* wc_w1    = (const float*)d_in[3];
    const float* wc_b1    = (const float*)d_in[4];
    const float* wc_g     = (const float*)d_in[5];
    const float* wc_beta  = (const float*)d_in[6];
    const float* wc_w2    = (const float*)d_in[7];
    const float* wc_b2    = (const float*)d_in[8];
    const float* enc_w1   = (const float*)d_in[9];
    const float* enc_b1   = (const float*)d_in[10];
    const float* enc_g1   = (const float*)d_in[11];
    const float* enc_beta1= (const float*)d_in[12];
    const float* enc_w2   = (const float*)d_in[13];
    const float* enc_b2   = (const float*)d_in[14];
    const float* enc_g2   = (const float*)d_in[15];
    const float* enc_beta2= (const float*)d_in[16];
    const float* enc_w3   = (const float*)d_in[17];
    const float* enc_b3   = (const float*)d_in[18];
    const float* enc_g3   = (const float*)d_in[19];
    const float* enc_beta3= (const float*)d_in[20];
    const float* fc21_w   = (const float*)d_in[21];
    const float* fc21_b   = (const float*)d_in[22];
    const float* fc22_w   = (const float*)d_in[23];
    const float* fc22_b   = (const float*)d_in[24];
    const float* fc3_w    = (const float*)d_in[25];
    const float* fc3_b    = (const float*)d_in[26];
    const float* fc3_g    = (const float*)d_in[27];
    const float* fc3_beta = (const float*)d_in[28];
    const float* fc4_w    = (const float*)d_in[29];
    const float* fc4_b    = (const float*)d_in[30];

    float* out   = (float*)d_out;
    float* mu_x  = out;
    float* mu    = out + (size_t)B_DIM * D_DIM;
    float* lv    = mu + (size_t)B_DIM * Z_DIM;

    const size_t F1M = 1u << 20;
    float* wsf = (float*)d_ws;
    float*     P_WL  = wsf;                          // f32 partials / WL
    _Float16*  P16   = (_Float16*)wsf;               // f16 partials (same region)
    _Float16*  xh    = (_Float16*)(wsf + 4 * F1M);
    _Float16*  xl    = (_Float16*)(wsf + 6 * F1M);
    _Float16*  xm16  = (_Float16*)(wsf + 4 * F1M);
    float*     Ybf   = wsf + 6 * F1M;                // f32 Y (wc path)
    _Float16*  Yb16  = (_Float16*)(wsf + 6 * F1M);   // f16 Y (enc/dec paths)
    _Float16*  a2    = (_Float16*)(wsf + 8 * F1M);
    _Float16*  a3    = (_Float16*)(wsf + 9 * F1M);
    _Float16*  a4    = (_Float16*)(wsf + 9 * F1M + F1M / 2);
    _Float16*  zb16  = (_Float16*)(wsf + 10 * F1M);
    _Float16*  a5    = (_Float16*)(wsf + 10 * F1M + F1M / 2);
    float*     Hbuf  = wsf + 11 * F1M;
    _Float16*  Hh    = (_Float16*)(wsf + 12 * F1M);
    _Float16*  Hl    = (_Float16*)(wsf + 12 * F1M + F1M / 2);
    _Float16*  w1th  = (_Float16*)(wsf + 13 * F1M);
    _Float16*  w1tl  = (_Float16*)(wsf + 13 * F1M + F1M / 2);
    _Float16*  w2th  = (_Float16*)(wsf + 14 * F1M);
    _Float16*  w2tl  = (_Float16*)(wsf + 14 * F1M + F1M / 2);
    _Float16*  e1t   = (_Float16*)(wsf + 15 * F1M);
    _Float16*  e2t   = (_Float16*)(wsf + 16 * F1M);
    _Float16*  e3t   = (_Float16*)(wsf + 16 * F1M + F1M / 4);
    _Float16*  f21t  = (_Float16*)(wsf + 16 * F1M + 3 * (F1M / 8));
    _Float16*  f22t  = (_Float16*)(wsf + 16 * F1M + 4 * (F1M / 8));  // contiguous after f21t
    _Float16*  f3t   = (_Float16*)(wsf + 16 * F1M + 5 * (F1M / 8));
    _Float16*  f4t   = (_Float16*)(wsf + 16 * F1M + 6 * (F1M / 8));
    float*     bnp   = wsf + 17 * F1M + F1M / 4;
    float*     scale = bnp + 131072;
    float*     shift = scale + 2048;

    const int G = 64;

    auto gemm3 = [&](const _Float16* Ah, const _Float16* Al,
                     const _Float16* Bh, const _Float16* Bl,
                     const float* b, float* C, float* part,
                     int N, int K, int SK) {
        dim3 grid((N + 63) / 64, B_DIM / 128, SK);
        gemm_f16<128, 64, 3, 32, float><<<grid, 256, 0, stream>>>(
            Ah, Al, Bh, Bl, b, C, part, B_DIM, N, K, ACT_NONE, K / SK);
    };
    auto gemm1 = [&](const _Float16* Ah, const _Float16* Bh,
                     const float* b, float* C, _Float16* part,
                     int N, int K, int act, int SK) {
        dim3 grid((N + 63) / 64, B_DIM / 128, SK);
        gemm_f16<128, 64, 1, 64, _Float16><<<grid, 256, 0, stream>>>(
            Ah, nullptr, Bh, nullptr, b, C, part, B_DIM, N, K, act, K / SK);
    };
    auto bnFromParts32 = [&](const float* part, int S, const float* b,
                             const float* g_, const float* beta_,
                             float* Y, _Float16* oh, _Float16* ol, int N, int act) {
        dim3 gp(N / 64, G);
        reduce_stats<float, float><<<gp, 256, 0, stream>>>(part, S, B_DIM, N, B_DIM / G, b, Y, bnp);
        colstats_final<<<(N + 255) / 256, 256, 0, stream>>>(bnp, G, N, B_DIM, g_, beta_, scale, shift);
        int total = B_DIM * N;
        bn_apply_f16<float><<<(total / 4 + 255) / 256, 256, 0, stream>>>(Y, scale, shift, oh, ol, total, N, act);
    };
    auto bnFromParts16 = [&](const _Float16* part, int S, const float* b,
                             const float* g_, const float* beta_,
                             _Float16* Y, _Float16* oh, _Float16* ol, int N, int act) {
        dim3 gp(N / 64, G);
        reduce_stats<_Float16, _Float16><<<gp, 256, 0, stream>>>(part, S, B_DIM, N, B_DIM / G, b, Y, bnp);
        colstats_final<<<(N + 255) / 256, 256, 0, stream>>>(bnp, G, N, B_DIM, g_, beta_, scale, shift);
        int total = B_DIM * N;
        bn_apply_f16<_Float16><<<(total / 4 + 255) / 256, 256, 0, stream>>>(Y, scale, shift, oh, ol, total, N, act);
    };
    auto cvtw = [&](const float* in, _Float16* oh, _Float16* ol, int K, int N, int Kp, int Np) {
        dim3 grid(Kp / 32, Np / 32);
        cvt_w_t<<<grid, 256, 0, stream>>>(in, oh, ol, K, N, Kp);
    };

    // ---- converts ----
    cvt_split_x<<<4096, 256, 0, stream>>>(x, xh, xl, B_DIM * D_DIM / 4);
    cvtw(wc_w1, w1th, w1tl, 2048, 512, 2048, 512);
    cvtw(wc_w2, w2th, w2tl, 512, 2048, 512, 2048);
    cvtw(enc_w1, e1t, nullptr, 2048, 1024, 2048, 1024);
    cvtw(enc_w2, e2t, nullptr, 1024, 512, 1024, 512);
    cvtw(enc_w3, e3t, nullptr, 512, 512, 512, 512);
    cvtw(fc21_w, f21t, nullptr, 512, 500, 512, 512);
    cvtw(fc22_w, f22t, nullptr, 512, 500, 512, 512);
    cvtw(fc3_w, f3t, nullptr, 500, 512, 512, 512);
    cvtw(fc4_w, f4t, nullptr, 512, 2048, 512, 2048);

    // ---- weight_creator (fp32-class path: f32 partials + f32 Y) ----
    gemm3(xh, xl, w1th, w1tl, nullptr, nullptr, P_WL, 512, 2048, 4);
    bnFromParts32(P_WL, 4, wc_b1, wc_g, wc_beta, Hbuf, Hh, Hl, 512, ACT_RELU);
    gemm3(Hh, Hl, w2th, w2tl, wc_b2, P_WL, nullptr, 2048, 512, 1);  // -> WL

    // ---- gumbel scan: WL -> xm16 (f16), block (4 waves) per row ----
    gumbel_scan<<<B_DIM, 256, 0, stream>>>(P_WL, u_gumbel, x, xm16);

    // ---- encoder (f16 partials + f16 Y) ----
    gemm1(xm16, e1t, nullptr, nullptr, P16, 1024, 2048, ACT_NONE, 2);
    bnFromParts16(P16, 2, enc_b1, enc_g1, enc_beta1, Yb16, a2, nullptr, 1024, ACT_LEAKY);
    gemm1(a2, e2t, nullptr, nullptr, P16, 512, 1024, ACT_NONE, 4);
    bnFromParts16(P16, 4, enc_b2, enc_g2, enc_beta2, Yb16, a3, nullptr, 512, ACT_LEAKY);
    gemm1(a3, e3t, nullptr, nullptr, P16, 512, 512, ACT_NONE, 4);
    bnFromParts16(P16, 4, enc_b3, enc_g3, enc_beta3, Yb16, a4, nullptr, 512, ACT_LEAKY);

    // ---- heads: combined GEMM + fused reduce/reparam (mu, lv, zb16) ----
    gemm1(a4, f21t, nullptr, nullptr, P16, 1024, 512, ACT_NONE, 4);
    reduce_heads_z<<<(B_DIM * 512 + 255) / 256, 256, 0, stream>>>(
        P16, 4, fc21_b, fc22_b, eps, mu, lv, zb16);

    // ---- decoder ----
    gemm1(zb16, f3t, nullptr, nullptr, P16, 512, 512, ACT_NONE, 4);
    bnFromParts16(P16, 4, fc3_b, fc3_g, fc3_beta, Yb16, a5, nullptr, 512, ACT_LEAKY);
    gemm1(a5, f4t, fc4_b, mu_x, nullptr, 2048, 512, ACT_SIGMOID, 1);
}